// Round 2
// baseline (946.884 us; speedup 1.0000x reference)
//
#include <hip/hip_runtime.h>
#include <math.h>

#define N_NODES 100000
#define N_EDGES 1600000
#define LN_EPS 1e-5f

__device__ __forceinline__ float sigmoidf_(float v) { return 1.0f / (1.0f + __expf(-v)); }
__device__ __forceinline__ float siluf_(float v) { return v * sigmoidf_(v); }

// bf16 pack/unpack helpers (RN pack via float bit-trick with round-to-nearest-even)
__device__ __forceinline__ unsigned short f2bf_(float f) {
    unsigned int u = __float_as_uint(f);
    unsigned int rounded = u + 0x7FFF + ((u >> 16) & 1);
    return (unsigned short)(rounded >> 16);
}

// ---------------------------------------------------------------------------
// K1: y[n][j] = silu( (x @ agg_W)[n][j] + agg_b[j] )   (N x 128) @ (128 x 128)
// stored as bf16. 8 nodes per block of 128 threads; x tile in LDS (float4).
// ---------------------------------------------------------------------------
__global__ __launch_bounds__(128) void k1_y(const float* __restrict__ x,
                                            const float* __restrict__ W,
                                            const float* __restrict__ b,
                                            unsigned short* __restrict__ y16) {
    __shared__ float4 xs4[8 * 32];
    const int j = threadIdx.x;          // output feature 0..127
    const int n0 = blockIdx.x * 8;
    const float4* x4 = (const float4*)x;
    xs4[j] = x4[n0 * 32 + j];
    xs4[j + 128] = x4[n0 * 32 + 128 + j];
    __syncthreads();

    float acc[8] = {0.f, 0.f, 0.f, 0.f, 0.f, 0.f, 0.f, 0.f};
#pragma unroll 8
    for (int k4 = 0; k4 < 32; ++k4) {
        const float w0 = W[(4 * k4 + 0) * 128 + j];
        const float w1 = W[(4 * k4 + 1) * 128 + j];
        const float w2 = W[(4 * k4 + 2) * 128 + j];
        const float w3 = W[(4 * k4 + 3) * 128 + j];
#pragma unroll
        for (int i = 0; i < 8; ++i) {
            const float4 v = xs4[i * 32 + k4];
            acc[i] = fmaf(v.x, w0, acc[i]);
            acc[i] = fmaf(v.y, w1, acc[i]);
            acc[i] = fmaf(v.z, w2, acc[i]);
            acc[i] = fmaf(v.w, w3, acc[i]);
        }
    }
    const float bj = b[j];
#pragma unroll
    for (int i = 0; i < 8; ++i)
        y16[(n0 + i) * 128 + j] = f2bf_(siluf_(acc[i] + bj));
}

// ---------------------------------------------------------------------------
// K2: per-edge gate  ew[e] = sigmoid( silu(attr[e] @ W1 + b1) @ W2 + b2 )
// ---------------------------------------------------------------------------
__global__ __launch_bounds__(256) void k2_ew(const float* __restrict__ attr,
                                             const float* __restrict__ W1,
                                             const float* __restrict__ b1,
                                             const float* __restrict__ W2,
                                             const float* __restrict__ b2,
                                             float* __restrict__ ew) {
    __shared__ float4 W1s[128];  // [k*32 + j4], k=0..3, j4=0..31
    __shared__ float4 W2s[32];
    __shared__ float4 b1s[32];
    const int t = threadIdx.x;
    if (t < 128) W1s[t] = ((const float4*)W1)[t];
    if (t < 32) {
        W2s[t] = ((const float4*)W2)[t];
        b1s[t] = ((const float4*)b1)[t];
    }
    __syncthreads();

    const int e = blockIdx.x * 256 + t;
    const float4 a = ((const float4*)attr)[e];
    float acc = 0.f;
#pragma unroll 8
    for (int j4 = 0; j4 < 32; ++j4) {
        const float4 r0 = W1s[j4];
        const float4 r1 = W1s[32 + j4];
        const float4 r2 = W1s[64 + j4];
        const float4 r3 = W1s[96 + j4];
        const float4 bb = b1s[j4];
        const float4 w2v = W2s[j4];
        float hx = fmaf(a.x, r0.x, fmaf(a.y, r1.x, fmaf(a.z, r2.x, fmaf(a.w, r3.x, bb.x))));
        float hy = fmaf(a.x, r0.y, fmaf(a.y, r1.y, fmaf(a.z, r2.y, fmaf(a.w, r3.y, bb.y))));
        float hz = fmaf(a.x, r0.z, fmaf(a.y, r1.z, fmaf(a.z, r2.z, fmaf(a.w, r3.z, bb.z))));
        float hw = fmaf(a.x, r0.w, fmaf(a.y, r1.w, fmaf(a.z, r2.w, fmaf(a.w, r3.w, bb.w))));
        acc = fmaf(siluf_(hx), w2v.x, acc);
        acc = fmaf(siluf_(hy), w2v.y, acc);
        acc = fmaf(siluf_(hz), w2v.z, acc);
        acc = fmaf(siluf_(hw), w2v.w, acc);
    }
    ew[e] = sigmoidf_(acc + b2[0]);
}

// ---------------------------------------------------------------------------
// P1: in-degree histogram (int atomics)
// ---------------------------------------------------------------------------
__global__ __launch_bounds__(256) void p1_hist(const int* __restrict__ dst,
                                               int* __restrict__ cnt) {
    const int e = blockIdx.x * 256 + threadIdx.x;
    atomicAdd(&cnt[dst[e]], 1);
}

// ---------------------------------------------------------------------------
// P2: unordered segment allocation (wave scan + one atomic bump per wave)
// ---------------------------------------------------------------------------
__global__ __launch_bounds__(256) void p2_alloc(const int* __restrict__ cnt,
                                                int* __restrict__ row_start,
                                                int* __restrict__ cursor,
                                                int* __restrict__ alloc) {
    const int n = blockIdx.x * 256 + threadIdx.x;
    const int lane = threadIdx.x & 63;
    const int c = (n < N_NODES) ? cnt[n] : 0;
    int s = c;
#pragma unroll
    for (int off = 1; off < 64; off <<= 1) {
        const int v = __shfl_up(s, off, 64);
        if (lane >= off) s += v;
    }
    const int total = __shfl(s, 63, 64);
    int base = 0;
    if (lane == 63) base = atomicAdd(alloc, total);
    base = __shfl(base, 63, 64);
    if (n < N_NODES) {
        const int st = base + s - c;
        row_start[n] = st;
        cursor[n] = st;
    }
}

// ---------------------------------------------------------------------------
// P3: scatter edges into their dst segment (slot via int atomic bump)
// ---------------------------------------------------------------------------
__global__ __launch_bounds__(256) void p3_fill(const int* __restrict__ src,
                                               const int* __restrict__ dst,
                                               const float* __restrict__ ew,
                                               int* __restrict__ cursor,
                                               int* __restrict__ src_sorted,
                                               float* __restrict__ ew_sorted) {
    const int e = blockIdx.x * 256 + threadIdx.x;
    const int d = dst[e];
    const int slot = atomicAdd(&cursor[d], 1);
    src_sorted[slot] = src[e];
    ew_sorted[slot] = ew[e];
}

// ---------------------------------------------------------------------------
// P4: per-node gather-aggregate from bf16 y:
//   agg[n] = (1/max(deg,1)) * sum_e ew[e]*y[src[e]]   -> written into d_out
// One wave per node; lane loads 4B (2 bf16). Zero fp32 atomics.
// ---------------------------------------------------------------------------
__global__ __launch_bounds__(256) void p4_agg(const unsigned short* __restrict__ y16,
                                              const int* __restrict__ row_start,
                                              const int* __restrict__ cnt,
                                              const int* __restrict__ src_sorted,
                                              const float* __restrict__ ew_sorted,
                                              float* __restrict__ agg) {
    const int wid = threadIdx.x >> 6;
    const int lane = threadIdx.x & 63;
    const int n = blockIdx.x * 4 + wid;
    const int st = row_start[n];
    const int c = cnt[n];
    float accx = 0.f, accy = 0.f;
    const unsigned int* y32 = (const unsigned int*)y16;  // 2 bf16 per uint
    for (int p = st; p < st + c; ++p) {
        const int s = src_sorted[p];
        const float w = ew_sorted[p];
        const unsigned int u = y32[s * 64 + lane];
        const float vx = __uint_as_float(u << 16);          // low bf16
        const float vy = __uint_as_float(u & 0xFFFF0000u);  // high bf16
        accx = fmaf(vx, w, accx);
        accy = fmaf(vy, w, accy);
    }
    const float inv = 1.0f / fmaxf((float)c, 1.0f);
    ((float2*)agg)[n * 64 + lane] = make_float2(accx * inv, accy * inv);
}

// ---------------------------------------------------------------------------
// K4: fused update MLP + residual + LayerNorm. agg aliases d_out: each block
// reads only its own 8 rows (before its own writes) — no cross-block hazard.
// ---------------------------------------------------------------------------
__global__ __launch_bounds__(128) void k4_update(const float* __restrict__ x,
                                                 const float* __restrict__ agg,
                                                 const float* __restrict__ W1,
                                                 const float* __restrict__ b1,
                                                 const float* __restrict__ W2,
                                                 const float* __restrict__ b2,
                                                 const float* __restrict__ lng,
                                                 const float* __restrict__ lnb,
                                                 const float* __restrict__ resW,
                                                 float* __restrict__ out) {
    __shared__ float4 cat4[8 * 64];  // [i][k4], k4 0..31 = x, 32..63 = agg (8 KB)
    __shared__ float4 h1s4[8 * 32];  // 4 KB
    float* h1s = (float*)h1s4;
    const int j = threadIdx.x;
    const int n0 = blockIdx.x * 8;
    const float4* x4 = (const float4*)x;
    const float4* agg4 = (const float4*)agg;

#pragma unroll
    for (int r = 0; r < 2; ++r) {
        const int idx = j + r * 128;       // 0..255
        const int i = idx >> 5, k4 = idx & 31;
        cat4[i * 64 + k4] = x4[(n0 + i) * 32 + k4];
        cat4[i * 64 + 32 + k4] = agg4[(n0 + i) * 32 + k4];
    }
    __syncthreads();

    // layer 1: K = 256
    float acc[8] = {0.f, 0.f, 0.f, 0.f, 0.f, 0.f, 0.f, 0.f};
#pragma unroll 4
    for (int k4 = 0; k4 < 64; ++k4) {
        const float w0 = W1[(4 * k4 + 0) * 128 + j];
        const float w1 = W1[(4 * k4 + 1) * 128 + j];
        const float w2 = W1[(4 * k4 + 2) * 128 + j];
        const float w3 = W1[(4 * k4 + 3) * 128 + j];
#pragma unroll
        for (int i = 0; i < 8; ++i) {
            const float4 v = cat4[i * 64 + k4];
            acc[i] = fmaf(v.x, w0, fmaf(v.y, w1, fmaf(v.z, w2, fmaf(v.w, w3, acc[i]))));
        }
    }
    const float b1j = b1[j];
#pragma unroll
    for (int i = 0; i < 8; ++i) h1s[i * 128 + j] = siluf_(acc[i] + b1j);
    __syncthreads();

    // layer 2 + residual: K = 128 each
    const float b2j = b2[j];
    float acc2[8];
#pragma unroll
    for (int i = 0; i < 8; ++i) acc2[i] = b2j;
#pragma unroll 2
    for (int k4 = 0; k4 < 32; ++k4) {
        const float u0 = W2[(4 * k4 + 0) * 128 + j];
        const float u1 = W2[(4 * k4 + 1) * 128 + j];
        const float u2 = W2[(4 * k4 + 2) * 128 + j];
        const float u3 = W2[(4 * k4 + 3) * 128 + j];
        const float r0 = resW[(4 * k4 + 0) * 128 + j];
        const float r1 = resW[(4 * k4 + 1) * 128 + j];
        const float r2 = resW[(4 * k4 + 2) * 128 + j];
        const float r3 = resW[(4 * k4 + 3) * 128 + j];
#pragma unroll
        for (int i = 0; i < 8; ++i) {
            const float4 hv = h1s4[i * 32 + k4];
            const float4 xv = cat4[i * 64 + k4];
            acc2[i] = fmaf(hv.x, u0, fmaf(hv.y, u1, fmaf(hv.z, u2, fmaf(hv.w, u3, acc2[i]))));
            acc2[i] = fmaf(xv.x, r0, fmaf(xv.y, r1, fmaf(xv.z, r2, fmaf(xv.w, r3, acc2[i]))));
        }
    }

    // LayerNorm across the 128 features (= 128 threads, 2 waves)
    float s[8], q[8];
#pragma unroll
    for (int i = 0; i < 8; ++i) {
        s[i] = acc2[i];
        q[i] = acc2[i] * acc2[i];
    }
#pragma unroll
    for (int off = 32; off >= 1; off >>= 1) {
#pragma unroll
        for (int i = 0; i < 8; ++i) {
            s[i] += __shfl_xor(s[i], off, 64);
            q[i] += __shfl_xor(q[i], off, 64);
        }
    }
    __shared__ float reds[2][8];
    __shared__ float redq[2][8];
    const int wid = j >> 6;
    const int lane = j & 63;
    if (lane == 0) {
#pragma unroll
        for (int i = 0; i < 8; ++i) {
            reds[wid][i] = s[i];
            redq[wid][i] = q[i];
        }
    }
    __syncthreads();
    const float gj = lng[j], bj = lnb[j];
#pragma unroll
    for (int i = 0; i < 8; ++i) {
        const float ts = reds[0][i] + reds[1][i];
        const float tq = redq[0][i] + redq[1][i];
        const float mu = ts * (1.0f / 128.0f);
        const float var = fmaxf(tq * (1.0f / 128.0f) - mu * mu, 0.f);
        const float rs = rsqrtf(var + LN_EPS);
        out[(n0 + i) * 128 + j] = (acc2[i] - mu) * rs * gj + bj;
    }
}

// ---------------------------------------------------------------------------
extern "C" void kernel_launch(void* const* d_in, const int* in_sizes, int n_in,
                              void* d_out, int out_size, void* d_ws, size_t ws_size,
                              hipStream_t stream) {
    const float* x = (const float*)d_in[0];
    const int* ei = (const int*)d_in[1];
    const float* eattr = (const float*)d_in[2];
    const float* aggW = (const float*)d_in[3];
    const float* aggb = (const float*)d_in[4];
    const float* eW1 = (const float*)d_in[5];
    const float* eb1 = (const float*)d_in[6];
    const float* eW2 = (const float*)d_in[7];
    const float* eb2 = (const float*)d_in[8];
    const float* uW1 = (const float*)d_in[9];
    const float* ub1 = (const float*)d_in[10];
    const float* uW2 = (const float*)d_in[11];
    const float* ub2 = (const float*)d_in[12];
    const float* lng = (const float*)d_in[13];
    const float* lnb = (const float*)d_in[14];
    const float* resW = (const float*)d_in[15];
    float* out = (float*)d_out;

    // workspace layout (bytes) — total 46,000,004 B (< out bytes = 51.2 MB)
    char* ws = (char*)d_ws;
    unsigned short* y16 = (unsigned short*)(ws + 0);  // N*128*2 = 25.6 MB
    float* ew = (float*)(ws + 25600000);              // E*4 = 6.4 MB
    float* ew_s = (float*)(ws + 32000000);            // 6.4 MB
    int* src_s = (int*)(ws + 38400000);               // 6.4 MB
    int* cnt = (int*)(ws + 44800000);                 // 0.4 MB
    int* alloc = (int*)(ws + 45200000);               // 4 B (adjacent to cnt: one memset)
    int* rowst = (int*)(ws + 45200004);               // 0.4 MB
    int* cursor = (int*)(ws + 45600004);              // 0.4 MB
    float* agg = out;                                 // aliased onto d_out (safe, see K4)

    const int* src = ei;             // edge_index[0]
    const int* dst = ei + N_EDGES;   // edge_index[1]

    hipMemsetAsync(cnt, 0, N_NODES * 4 + 4, stream);  // cnt + alloc

    k1_y<<<N_NODES / 8, 128, 0, stream>>>(x, aggW, aggb, y16);
    k2_ew<<<N_EDGES / 256, 256, 0, stream>>>(eattr, eW1, eb1, eW2, eb2, ew);
    p1_hist<<<N_EDGES / 256, 256, 0, stream>>>(dst, cnt);
    p2_alloc<<<(N_NODES + 255) / 256, 256, 0, stream>>>(cnt, rowst, cursor, alloc);
    p3_fill<<<N_EDGES / 256, 256, 0, stream>>>(src, dst, ew, cursor, src_s, ew_s);
    p4_agg<<<N_NODES / 4, 256, 0, stream>>>(y16, rowst, cnt, src_s, ew_s, agg);
    k4_update<<<N_NODES / 8, 128, 0, stream>>>(x, agg, uW1, ub1, uW2, ub2, lng, lnb, resW, out);
}

// Round 3
// 661.445 us; speedup vs baseline: 1.4315x; 1.4315x over previous
//
#include <hip/hip_runtime.h>
#include <math.h>

#define N_NODES 100000
#define N_EDGES 1600000
#define LN_EPS 1e-5f

typedef __attribute__((ext_vector_type(8))) short short8;
typedef __attribute__((ext_vector_type(4))) float f32x4;
#define MFMA16(a, b, c) __builtin_amdgcn_mfma_f32_16x16x32_bf16(a, b, c, 0, 0, 0)

__device__ __forceinline__ float sigmoidf_(float v) { return 1.0f / (1.0f + __expf(-v)); }
__device__ __forceinline__ float siluf_(float v) { return v * sigmoidf_(v); }

// bf16 pack (round-to-nearest-even)
__device__ __forceinline__ unsigned short f2bf_(float f) {
    unsigned int u = __float_as_uint(f);
    unsigned int rounded = u + 0x7FFF + ((u >> 16) & 1);
    return (unsigned short)(rounded >> 16);
}

// ---------------------------------------------------------------------------
// KW: convert + transpose weights to bf16 [n][k] so MFMA B-fragments are
// contiguous 16B loads. w1t: 128x256, w2t/rest/aggt: 128x128.
// ---------------------------------------------------------------------------
__global__ __launch_bounds__(256) void kw(const float* __restrict__ W1,
                                          const float* __restrict__ W2,
                                          const float* __restrict__ resW,
                                          const float* __restrict__ aggW,
                                          unsigned short* __restrict__ w1t,
                                          unsigned short* __restrict__ w2t,
                                          unsigned short* __restrict__ rest,
                                          unsigned short* __restrict__ aggt) {
    const int idx = blockIdx.x * 256 + threadIdx.x;  // 0..81919
    if (idx < 32768) {
        const int n = idx >> 8, k = idx & 255;
        w1t[idx] = f2bf_(W1[k * 128 + n]);
    } else if (idx < 49152) {
        const int i = idx - 32768, n = i >> 7, k = i & 127;
        w2t[i] = f2bf_(W2[k * 128 + n]);
    } else if (idx < 65536) {
        const int i = idx - 49152, n = i >> 7, k = i & 127;
        rest[i] = f2bf_(resW[k * 128 + n]);
    } else {
        const int i = idx - 65536, n = i >> 7, k = i & 127;
        aggt[i] = f2bf_(aggW[k * 128 + n]);
    }
}

// ---------------------------------------------------------------------------
// K1 (MFMA): y16 = bf16( silu(x @ aggW + b) ).  32 nodes/block, 256 thr.
// A (x, bf16) staged in LDS stride 136 (+8 pad -> bank-balanced b128 reads).
// Wave w computes cols [w*32, w*32+32) for all 32 nodes (2 Mtiles x 2 Ntiles).
// ---------------------------------------------------------------------------
__global__ __launch_bounds__(256) void k1_y(const float* __restrict__ x,
                                            const unsigned short* __restrict__ aggt,
                                            const float* __restrict__ b,
                                            unsigned short* __restrict__ y16) {
    __shared__ unsigned short A1[32 * 136];
    __shared__ unsigned short O[32 * 136];
    const int t = threadIdx.x;
    const int n0 = blockIdx.x * 32;
    const float4* x4 = (const float4*)x;

#pragma unroll
    for (int r = 0; r < 4; ++r) {
        const int idx = t + r * 256;          // 0..1023 = 32 nodes x 32 float4
        const int node = idx >> 5, c4 = idx & 31;
        const float4 v = x4[(n0 + node) * 32 + c4];
        ushort4 p;
        p.x = f2bf_(v.x); p.y = f2bf_(v.y); p.z = f2bf_(v.z); p.w = f2bf_(v.w);
        *(ushort4*)&A1[node * 136 + c4 * 4] = p;
    }
    __syncthreads();

    const int w = t >> 6, lane = t & 63, nq = lane & 15, quad = lane >> 4;
    f32x4 c[2][2] = {};
#pragma unroll
    for (int ks = 0; ks < 4; ++ks) {
        const int k0 = ks * 32 + quad * 8;
        const short8 a0 = *(const short8*)&A1[(nq)*136 + k0];
        const short8 a1 = *(const short8*)&A1[(16 + nq) * 136 + k0];
        const short8 b0 = *(const short8*)&aggt[(w * 32 + nq) * 128 + k0];
        const short8 b1 = *(const short8*)&aggt[(w * 32 + 16 + nq) * 128 + k0];
        c[0][0] = MFMA16(a0, b0, c[0][0]);
        c[0][1] = MFMA16(a0, b1, c[0][1]);
        c[1][0] = MFMA16(a1, b0, c[1][0]);
        c[1][1] = MFMA16(a1, b1, c[1][1]);
    }
    const float bc0 = b[w * 32 + nq], bc1 = b[w * 32 + 16 + nq];
#pragma unroll
    for (int mt = 0; mt < 2; ++mt)
#pragma unroll
        for (int r = 0; r < 4; ++r) {
            const int row = mt * 16 + quad * 4 + r;
            O[row * 136 + w * 32 + nq] = f2bf_(siluf_(c[mt][0][r] + bc0));
            O[row * 136 + w * 32 + 16 + nq] = f2bf_(siluf_(c[mt][1][r] + bc1));
        }
    __syncthreads();

#pragma unroll
    for (int r = 0; r < 2; ++r) {
        const int idx = t + r * 256;          // 0..511 = 32 rows x 16 chunks(16B)
        const int row = idx >> 4, c8 = idx & 15;
        const short8 v = *(const short8*)&O[row * 136 + c8 * 8];
        *(short8*)&y16[(n0 + row) * 128 + c8 * 8] = v;
    }
}

// ---------------------------------------------------------------------------
// K2: per-edge gate  ew[e] = sigmoid( silu(attr[e] @ W1 + b1) @ W2 + b2 )
// ---------------------------------------------------------------------------
__global__ __launch_bounds__(256) void k2_ew(const float* __restrict__ attr,
                                             const float* __restrict__ W1,
                                             const float* __restrict__ b1,
                                             const float* __restrict__ W2,
                                             const float* __restrict__ b2,
                                             float* __restrict__ ew) {
    __shared__ float4 W1s[128];
    __shared__ float4 W2s[32];
    __shared__ float4 b1s[32];
    const int t = threadIdx.x;
    if (t < 128) W1s[t] = ((const float4*)W1)[t];
    if (t < 32) {
        W2s[t] = ((const float4*)W2)[t];
        b1s[t] = ((const float4*)b1)[t];
    }
    __syncthreads();

    const int e = blockIdx.x * 256 + t;
    const float4 a = ((const float4*)attr)[e];
    float acc = 0.f;
#pragma unroll 8
    for (int j4 = 0; j4 < 32; ++j4) {
        const float4 r0 = W1s[j4];
        const float4 r1 = W1s[32 + j4];
        const float4 r2 = W1s[64 + j4];
        const float4 r3 = W1s[96 + j4];
        const float4 bb = b1s[j4];
        const float4 w2v = W2s[j4];
        float hx = fmaf(a.x, r0.x, fmaf(a.y, r1.x, fmaf(a.z, r2.x, fmaf(a.w, r3.x, bb.x))));
        float hy = fmaf(a.x, r0.y, fmaf(a.y, r1.y, fmaf(a.z, r2.y, fmaf(a.w, r3.y, bb.y))));
        float hz = fmaf(a.x, r0.z, fmaf(a.y, r1.z, fmaf(a.z, r2.z, fmaf(a.w, r3.z, bb.z))));
        float hw = fmaf(a.x, r0.w, fmaf(a.y, r1.w, fmaf(a.z, r2.w, fmaf(a.w, r3.w, bb.w))));
        acc = fmaf(siluf_(hx), w2v.x, acc);
        acc = fmaf(siluf_(hy), w2v.y, acc);
        acc = fmaf(siluf_(hz), w2v.z, acc);
        acc = fmaf(siluf_(hw), w2v.w, acc);
    }
    ew[e] = sigmoidf_(acc + b2[0]);
}

// ---------------------------------------------------------------------------
// P1: in-degree histogram
// ---------------------------------------------------------------------------
__global__ __launch_bounds__(256) void p1_hist(const int* __restrict__ dst,
                                               int* __restrict__ cnt) {
    const int e = blockIdx.x * 256 + threadIdx.x;
    atomicAdd(&cnt[dst[e]], 1);
}

// ---------------------------------------------------------------------------
// P2: unordered segment allocation (wave scan + one atomic bump per wave)
// ---------------------------------------------------------------------------
__global__ __launch_bounds__(256) void p2_alloc(const int* __restrict__ cnt,
                                                int* __restrict__ row_start,
                                                int* __restrict__ cursor,
                                                int* __restrict__ alloc) {
    const int n = blockIdx.x * 256 + threadIdx.x;
    const int lane = threadIdx.x & 63;
    const int c = (n < N_NODES) ? cnt[n] : 0;
    int s = c;
#pragma unroll
    for (int off = 1; off < 64; off <<= 1) {
        const int v = __shfl_up(s, off, 64);
        if (lane >= off) s += v;
    }
    const int total = __shfl(s, 63, 64);
    int base = 0;
    if (lane == 63) base = atomicAdd(alloc, total);
    base = __shfl(base, 63, 64);
    if (n < N_NODES) {
        const int st = base + s - c;
        row_start[n] = st;
        cursor[n] = st;
    }
}

// ---------------------------------------------------------------------------
// P3: scatter edges into their dst segment (slot via int atomic bump)
// ---------------------------------------------------------------------------
__global__ __launch_bounds__(256) void p3_fill(const int* __restrict__ src,
                                               const int* __restrict__ dst,
                                               const float* __restrict__ ew,
                                               int* __restrict__ cursor,
                                               int* __restrict__ src_sorted,
                                               float* __restrict__ ew_sorted) {
    const int e = blockIdx.x * 256 + threadIdx.x;
    const int d = dst[e];
    const int slot = atomicAdd(&cursor[d], 1);
    src_sorted[slot] = src[e];
    ew_sorted[slot] = ew[e];
}

// ---------------------------------------------------------------------------
// P4: per-node gather-aggregate from bf16 y -> fp32 agg (aliased on d_out)
// ---------------------------------------------------------------------------
__global__ __launch_bounds__(256) void p4_agg(const unsigned short* __restrict__ y16,
                                              const int* __restrict__ row_start,
                                              const int* __restrict__ cnt,
                                              const int* __restrict__ src_sorted,
                                              const float* __restrict__ ew_sorted,
                                              float* __restrict__ agg) {
    const int wid = threadIdx.x >> 6;
    const int lane = threadIdx.x & 63;
    const int n = blockIdx.x * 4 + wid;
    const int st = row_start[n];
    const int c = cnt[n];
    float accx = 0.f, accy = 0.f;
    const unsigned int* y32 = (const unsigned int*)y16;
    for (int p = st; p < st + c; ++p) {
        const int s = src_sorted[p];
        const float w = ew_sorted[p];
        const unsigned int u = y32[s * 64 + lane];
        const float vx = __uint_as_float(u << 16);
        const float vy = __uint_as_float(u & 0xFFFF0000u);
        accx = fmaf(vx, w, accx);
        accy = fmaf(vy, w, accy);
    }
    const float inv = 1.0f / fmaxf((float)c, 1.0f);
    ((float2*)agg)[n * 64 + lane] = make_float2(accx * inv, accy * inv);
}

// ---------------------------------------------------------------------------
// K4 (MFMA): fused update MLP + residual + LayerNorm.
//   h1 = silu([x, agg] @ W1 + b1); h2 = h1@W2 + x@resW + b2; out = LN(h2)
// 32 nodes/block, 256 thr (4 waves x 32 cols). agg aliases out (block-local
// rows read before written; syncthreads in between).
// ---------------------------------------------------------------------------
__global__ __launch_bounds__(256) void k4_update(const float* __restrict__ x,
                                                 const float* agg,
                                                 const unsigned short* __restrict__ w1t,
                                                 const float* __restrict__ b1,
                                                 const unsigned short* __restrict__ w2t,
                                                 const float* __restrict__ b2,
                                                 const float* __restrict__ lng,
                                                 const float* __restrict__ lnb,
                                                 const unsigned short* __restrict__ rest,
                                                 float* out) {
    __shared__ unsigned short A1[32 * 264];  // [m][k] cat(x,agg) bf16, +8 pad
    __shared__ unsigned short A2[32 * 136];  // [m][k] h1 bf16, +8 pad
    __shared__ float red_s[4][32];
    __shared__ float red_q[4][32];
    __shared__ float ln_mu[32];
    __shared__ float ln_rs[32];

    const int t = threadIdx.x;
    const int n0 = blockIdx.x * 32;
    const float4* x4 = (const float4*)x;
    const float4* agg4 = (const float4*)agg;

#pragma unroll
    for (int r = 0; r < 4; ++r) {
        const int idx = t + r * 256;          // 0..1023 = 32 nodes x 32 float4
        const int node = idx >> 5, c4 = idx & 31;
        const float4 vx = x4[(n0 + node) * 32 + c4];
        const float4 va = agg4[(n0 + node) * 32 + c4];
        ushort4 px, pa;
        px.x = f2bf_(vx.x); px.y = f2bf_(vx.y); px.z = f2bf_(vx.z); px.w = f2bf_(vx.w);
        pa.x = f2bf_(va.x); pa.y = f2bf_(va.y); pa.z = f2bf_(va.z); pa.w = f2bf_(va.w);
        *(ushort4*)&A1[node * 264 + c4 * 4] = px;
        *(ushort4*)&A1[node * 264 + 128 + c4 * 4] = pa;
    }
    __syncthreads();

    const int w = t >> 6, lane = t & 63, nq = lane & 15, quad = lane >> 4;

    // ---- layer 1: [32x256] @ [256x128] ----
    f32x4 c1[2][2] = {};
#pragma unroll
    for (int ks = 0; ks < 8; ++ks) {
        const int k0 = ks * 32 + quad * 8;
        const short8 a0 = *(const short8*)&A1[(nq)*264 + k0];
        const short8 a1 = *(const short8*)&A1[(16 + nq) * 264 + k0];
        const short8 b0 = *(const short8*)&w1t[(w * 32 + nq) * 256 + k0];
        const short8 b1f = *(const short8*)&w1t[(w * 32 + 16 + nq) * 256 + k0];
        c1[0][0] = MFMA16(a0, b0, c1[0][0]);
        c1[0][1] = MFMA16(a0, b1f, c1[0][1]);
        c1[1][0] = MFMA16(a1, b0, c1[1][0]);
        c1[1][1] = MFMA16(a1, b1f, c1[1][1]);
    }
    const float b1c0 = b1[w * 32 + nq], b1c1 = b1[w * 32 + 16 + nq];
#pragma unroll
    for (int mt = 0; mt < 2; ++mt)
#pragma unroll
        for (int r = 0; r < 4; ++r) {
            const int row = mt * 16 + quad * 4 + r;
            A2[row * 136 + w * 32 + nq] = f2bf_(siluf_(c1[mt][0][r] + b1c0));
            A2[row * 136 + w * 32 + 16 + nq] = f2bf_(siluf_(c1[mt][1][r] + b1c1));
        }
    __syncthreads();

    // ---- layer 2 + residual: h1@W2 + x@resW ----
    f32x4 c2[2][2] = {};
#pragma unroll
    for (int ks = 0; ks < 4; ++ks) {
        const int k0 = ks * 32 + quad * 8;
        const short8 a0 = *(const short8*)&A2[(nq)*136 + k0];
        const short8 a1 = *(const short8*)&A2[(16 + nq) * 136 + k0];
        const short8 b0 = *(const short8*)&w2t[(w * 32 + nq) * 128 + k0];
        const short8 b1f = *(const short8*)&w2t[(w * 32 + 16 + nq) * 128 + k0];
        c2[0][0] = MFMA16(a0, b0, c2[0][0]);
        c2[0][1] = MFMA16(a0, b1f, c2[0][1]);
        c2[1][0] = MFMA16(a1, b0, c2[1][0]);
        c2[1][1] = MFMA16(a1, b1f, c2[1][1]);
    }
#pragma unroll
    for (int ks = 0; ks < 4; ++ks) {
        const int k0 = ks * 32 + quad * 8;
        const short8 a0 = *(const short8*)&A1[(nq)*264 + k0];       // x half
        const short8 a1 = *(const short8*)&A1[(16 + nq) * 264 + k0];
        const short8 b0 = *(const short8*)&rest[(w * 32 + nq) * 128 + k0];
        const short8 b1f = *(const short8*)&rest[(w * 32 + 16 + nq) * 128 + k0];
        c2[0][0] = MFMA16(a0, b0, c2[0][0]);
        c2[0][1] = MFMA16(a0, b1f, c2[0][1]);
        c2[1][0] = MFMA16(a1, b0, c2[1][0]);
        c2[1][1] = MFMA16(a1, b1f, c2[1][1]);
    }

    // ---- LayerNorm ----
    const float b2c0 = b2[w * 32 + nq], b2c1 = b2[w * 32 + 16 + nq];
    float vals[2][2][4];
#pragma unroll
    for (int mt = 0; mt < 2; ++mt)
#pragma unroll
        for (int r = 0; r < 4; ++r) {
            vals[mt][0][r] = c2[mt][0][r] + b2c0;
            vals[mt][1][r] = c2[mt][1][r] + b2c1;
        }
#pragma unroll
    for (int mt = 0; mt < 2; ++mt)
#pragma unroll
        for (int r = 0; r < 4; ++r) {
            float s = vals[mt][0][r] + vals[mt][1][r];
            float q = vals[mt][0][r] * vals[mt][0][r] + vals[mt][1][r] * vals[mt][1][r];
#pragma unroll
            for (int off = 1; off <= 8; off <<= 1) {
                s += __shfl_xor(s, off, 64);
                q += __shfl_xor(q, off, 64);
            }
            if (nq == 0) {
                const int row = mt * 16 + quad * 4 + r;
                red_s[w][row] = s;
                red_q[w][row] = q;
            }
        }
    __syncthreads();
    if (t < 32) {
        const float ts = red_s[0][t] + red_s[1][t] + red_s[2][t] + red_s[3][t];
        const float tq = red_q[0][t] + red_q[1][t] + red_q[2][t] + red_q[3][t];
        const float mu = ts * (1.0f / 128.0f);
        const float var = fmaxf(tq * (1.0f / 128.0f) - mu * mu, 0.f);
        ln_mu[t] = mu;
        ln_rs[t] = rsqrtf(var + LN_EPS);
    }
    __syncthreads();

    const float g0 = lng[w * 32 + nq], g1 = lng[w * 32 + 16 + nq];
    const float lb0 = lnb[w * 32 + nq], lb1 = lnb[w * 32 + 16 + nq];
#pragma unroll
    for (int mt = 0; mt < 2; ++mt)
#pragma unroll
        for (int r = 0; r < 4; ++r) {
            const int row = mt * 16 + quad * 4 + r;
            const float mu = ln_mu[row], rs = ln_rs[row];
            out[(n0 + row) * 128 + w * 32 + nq] = (vals[mt][0][r] - mu) * rs * g0 + lb0;
            out[(n0 + row) * 128 + w * 32 + 16 + nq] = (vals[mt][1][r] - mu) * rs * g1 + lb1;
        }
}

// ---------------------------------------------------------------------------
extern "C" void kernel_launch(void* const* d_in, const int* in_sizes, int n_in,
                              void* d_out, int out_size, void* d_ws, size_t ws_size,
                              hipStream_t stream) {
    const float* x = (const float*)d_in[0];
    const int* ei = (const int*)d_in[1];
    const float* eattr = (const float*)d_in[2];
    const float* aggW = (const float*)d_in[3];
    const float* aggb = (const float*)d_in[4];
    const float* eW1 = (const float*)d_in[5];
    const float* eb1 = (const float*)d_in[6];
    const float* eW2 = (const float*)d_in[7];
    const float* eb2 = (const float*)d_in[8];
    const float* uW1 = (const float*)d_in[9];
    const float* ub1 = (const float*)d_in[10];
    const float* uW2 = (const float*)d_in[11];
    const float* ub2 = (const float*)d_in[12];
    const float* lng = (const float*)d_in[13];
    const float* lnb = (const float*)d_in[14];
    const float* resW = (const float*)d_in[15];
    float* out = (float*)d_out;

    // workspace layout (bytes) — total ~46.2 MB (< out bytes = 51.2 MB)
    char* ws = (char*)d_ws;
    unsigned short* y16 = (unsigned short*)(ws + 0);   // 25.6 MB
    float* ew = (float*)(ws + 25600000);               // 6.4 MB
    float* ew_s = (float*)(ws + 32000000);             // 6.4 MB
    int* src_s = (int*)(ws + 38400000);                // 6.4 MB
    int* cnt = (int*)(ws + 44800000);                  // 0.4 MB
    int* alloc = (int*)(ws + 45200000);                // 4 B
    int* rowst = (int*)(ws + 45200004);                // 0.4 MB
    int* cursor = (int*)(ws + 45600004);               // 0.4 MB -> 46,000,004
    unsigned short* w1t = (unsigned short*)(ws + 46000016);   // 65,536 B (16-aligned)
    unsigned short* w2t = (unsigned short*)(ws + 46065552);   // 32,768 B
    unsigned short* rest = (unsigned short*)(ws + 46098320);  // 32,768 B
    unsigned short* aggt = (unsigned short*)(ws + 46131088);  // 32,768 B -> 46,163,856
    float* agg = out;  // aliased onto d_out (safe: block-local rows, see K4)

    const int* src = ei;
    const int* dst = ei + N_EDGES;

    hipMemsetAsync(cnt, 0, N_NODES * 4 + 4, stream);  // cnt + alloc

    kw<<<320, 256, 0, stream>>>(uW1, uW2, resW, aggW, w1t, w2t, rest, aggt);
    k1_y<<<N_NODES / 32, 256, 0, stream>>>(x, aggt, aggb, y16);
    k2_ew<<<N_EDGES / 256, 256, 0, stream>>>(eattr, eW1, eb1, eW2, eb2, ew);
    p1_hist<<<N_EDGES / 256, 256, 0, stream>>>(dst, cnt);
    p2_alloc<<<(N_NODES + 255) / 256, 256, 0, stream>>>(cnt, rowst, cursor, alloc);
    p3_fill<<<N_EDGES / 256, 256, 0, stream>>>(src, dst, ew, cursor, src_s, ew_s);
    p4_agg<<<N_NODES / 4, 256, 0, stream>>>(y16, rowst, cnt, src_s, ew_s, agg);
    k4_update<<<N_NODES / 32, 256, 0, stream>>>(x, agg, w1t, ub1, w2t, ub2, lng, lnb, rest, out);
}

// Round 4
// 527.125 us; speedup vs baseline: 1.7963x; 1.2548x over previous
//
#include <hip/hip_runtime.h>
#include <math.h>

#define N_NODES 100000
#define N_EDGES 1600000
#define LN_EPS 1e-5f

typedef __attribute__((ext_vector_type(8))) short short8;
typedef __attribute__((ext_vector_type(4))) float f32x4;
#define MFMA16(a, b, c) __builtin_amdgcn_mfma_f32_16x16x32_bf16(a, b, c, 0, 0, 0)

__device__ __forceinline__ float sigmoidf_(float v) { return 1.0f / (1.0f + __expf(-v)); }
__device__ __forceinline__ float siluf_(float v) { return v * sigmoidf_(v); }

// bf16 pack (round-to-nearest-even)
__device__ __forceinline__ unsigned short f2bf_(float f) {
    unsigned int u = __float_as_uint(f);
    unsigned int rounded = u + 0x7FFF + ((u >> 16) & 1);
    return (unsigned short)(rounded >> 16);
}

// ---------------------------------------------------------------------------
// KW: convert + transpose weights to bf16 [n][k] (contiguous B-fragments).
// ---------------------------------------------------------------------------
__global__ __launch_bounds__(256) void kw(const float* __restrict__ W1,
                                          const float* __restrict__ W2,
                                          const float* __restrict__ resW,
                                          const float* __restrict__ aggW,
                                          unsigned short* __restrict__ w1t,
                                          unsigned short* __restrict__ w2t,
                                          unsigned short* __restrict__ rest,
                                          unsigned short* __restrict__ aggt) {
    const int idx = blockIdx.x * 256 + threadIdx.x;  // 0..81919
    if (idx < 32768) {
        const int n = idx >> 8, k = idx & 255;
        w1t[idx] = f2bf_(W1[k * 128 + n]);
    } else if (idx < 49152) {
        const int i = idx - 32768, n = i >> 7, k = i & 127;
        w2t[i] = f2bf_(W2[k * 128 + n]);
    } else if (idx < 65536) {
        const int i = idx - 49152, n = i >> 7, k = i & 127;
        rest[i] = f2bf_(resW[k * 128 + n]);
    } else {
        const int i = idx - 65536, n = i >> 7, k = i & 127;
        aggt[i] = f2bf_(aggW[k * 128 + n]);
    }
}

// ---------------------------------------------------------------------------
// K1 (MFMA): y16 = bf16( silu(x @ aggW + b) ).  32 nodes/block, 256 thr.
// ---------------------------------------------------------------------------
__global__ __launch_bounds__(256) void k1_y(const float* __restrict__ x,
                                            const unsigned short* __restrict__ aggt,
                                            const float* __restrict__ b,
                                            unsigned short* __restrict__ y16) {
    __shared__ unsigned short A1[32 * 136];
    __shared__ unsigned short O[32 * 136];
    const int t = threadIdx.x;
    const int n0 = blockIdx.x * 32;
    const float4* x4 = (const float4*)x;

#pragma unroll
    for (int r = 0; r < 4; ++r) {
        const int idx = t + r * 256;          // 32 nodes x 32 float4
        const int node = idx >> 5, c4 = idx & 31;
        const float4 v = x4[(n0 + node) * 32 + c4];
        ushort4 p;
        p.x = f2bf_(v.x); p.y = f2bf_(v.y); p.z = f2bf_(v.z); p.w = f2bf_(v.w);
        *(ushort4*)&A1[node * 136 + c4 * 4] = p;
    }
    __syncthreads();

    const int w = t >> 6, lane = t & 63, nq = lane & 15, quad = lane >> 4;
    f32x4 c[2][2] = {};
#pragma unroll
    for (int ks = 0; ks < 4; ++ks) {
        const int k0 = ks * 32 + quad * 8;
        const short8 a0 = *(const short8*)&A1[(nq)*136 + k0];
        const short8 a1 = *(const short8*)&A1[(16 + nq) * 136 + k0];
        const short8 b0 = *(const short8*)&aggt[(w * 32 + nq) * 128 + k0];
        const short8 b1 = *(const short8*)&aggt[(w * 32 + 16 + nq) * 128 + k0];
        c[0][0] = MFMA16(a0, b0, c[0][0]);
        c[0][1] = MFMA16(a0, b1, c[0][1]);
        c[1][0] = MFMA16(a1, b0, c[1][0]);
        c[1][1] = MFMA16(a1, b1, c[1][1]);
    }
    const float bc0 = b[w * 32 + nq], bc1 = b[w * 32 + 16 + nq];
#pragma unroll
    for (int mt = 0; mt < 2; ++mt)
#pragma unroll
        for (int r = 0; r < 4; ++r) {
            const int row = mt * 16 + quad * 4 + r;
            O[row * 136 + w * 32 + nq] = f2bf_(siluf_(c[mt][0][r] + bc0));
            O[row * 136 + w * 32 + 16 + nq] = f2bf_(siluf_(c[mt][1][r] + bc1));
        }
    __syncthreads();

#pragma unroll
    for (int r = 0; r < 2; ++r) {
        const int idx = t + r * 256;          // 32 rows x 16 chunks(16B)
        const int row = idx >> 4, c8 = idx & 15;
        const short8 v = *(const short8*)&O[row * 136 + c8 * 8];
        *(short8*)&y16[(n0 + row) * 128 + c8 * 8] = v;
    }
}

// ---------------------------------------------------------------------------
// PE1 (fused k2+p1): per-edge gate + in-degree histogram in one edge pass.
// ---------------------------------------------------------------------------
__global__ __launch_bounds__(256) void pe1(const float* __restrict__ attr,
                                           const float* __restrict__ W1,
                                           const float* __restrict__ b1,
                                           const float* __restrict__ W2,
                                           const float* __restrict__ b2,
                                           const int* __restrict__ dst,
                                           float* __restrict__ ew,
                                           int* __restrict__ cnt) {
    __shared__ float4 W1s[128];
    __shared__ float4 W2s[32];
    __shared__ float4 b1s[32];
    const int t = threadIdx.x;
    if (t < 128) W1s[t] = ((const float4*)W1)[t];
    if (t < 32) {
        W2s[t] = ((const float4*)W2)[t];
        b1s[t] = ((const float4*)b1)[t];
    }
    __syncthreads();

    const int e = blockIdx.x * 256 + t;
    const float4 a = ((const float4*)attr)[e];
    const int d = dst[e];
    float acc = 0.f;
#pragma unroll 8
    for (int j4 = 0; j4 < 32; ++j4) {
        const float4 r0 = W1s[j4];
        const float4 r1 = W1s[32 + j4];
        const float4 r2 = W1s[64 + j4];
        const float4 r3 = W1s[96 + j4];
        const float4 bb = b1s[j4];
        const float4 w2v = W2s[j4];
        float hx = fmaf(a.x, r0.x, fmaf(a.y, r1.x, fmaf(a.z, r2.x, fmaf(a.w, r3.x, bb.x))));
        float hy = fmaf(a.x, r0.y, fmaf(a.y, r1.y, fmaf(a.z, r2.y, fmaf(a.w, r3.y, bb.y))));
        float hz = fmaf(a.x, r0.z, fmaf(a.y, r1.z, fmaf(a.z, r2.z, fmaf(a.w, r3.z, bb.z))));
        float hw = fmaf(a.x, r0.w, fmaf(a.y, r1.w, fmaf(a.z, r2.w, fmaf(a.w, r3.w, bb.w))));
        acc = fmaf(siluf_(hx), w2v.x, acc);
        acc = fmaf(siluf_(hy), w2v.y, acc);
        acc = fmaf(siluf_(hz), w2v.z, acc);
        acc = fmaf(siluf_(hw), w2v.w, acc);
    }
    ew[e] = sigmoidf_(acc + b2[0]);
    atomicAdd(&cnt[d], 1);
}

// ---------------------------------------------------------------------------
// P2: unordered segment allocation (wave scan + one atomic bump per wave)
// ---------------------------------------------------------------------------
__global__ __launch_bounds__(256) void p2_alloc(const int* __restrict__ cnt,
                                                int* __restrict__ row_start,
                                                int* __restrict__ cursor,
                                                int* __restrict__ alloc) {
    const int n = blockIdx.x * 256 + threadIdx.x;
    const int lane = threadIdx.x & 63;
    const int c = (n < N_NODES) ? cnt[n] : 0;
    int s = c;
#pragma unroll
    for (int off = 1; off < 64; off <<= 1) {
        const int v = __shfl_up(s, off, 64);
        if (lane >= off) s += v;
    }
    const int total = __shfl(s, 63, 64);
    int base = 0;
    if (lane == 63) base = atomicAdd(alloc, total);
    base = __shfl(base, 63, 64);
    if (n < N_NODES) {
        const int st = base + s - c;
        row_start[n] = st;
        cursor[n] = st;
    }
}

// ---------------------------------------------------------------------------
// P3: scatter packed {src, ew} records into dst segments (atomic slot bump)
// ---------------------------------------------------------------------------
__global__ __launch_bounds__(256) void p3_fill(const int* __restrict__ src,
                                               const int* __restrict__ dst,
                                               const float* __restrict__ ew,
                                               int* __restrict__ cursor,
                                               uint2* __restrict__ rec) {
    const int e = blockIdx.x * 256 + threadIdx.x;
    const int d = dst[e];
    const int slot = atomicAdd(&cursor[d], 1);
    rec[slot] = make_uint2((unsigned)src[e], __float_as_uint(ew[e]));
}

// ---------------------------------------------------------------------------
// P4: per-node gather-aggregate from bf16 y -> fp32 agg (aliased on d_out).
// One wave per node; edge loop unrolled x4 (4 row-gathers in flight).
// ---------------------------------------------------------------------------
__global__ __launch_bounds__(256) void p4_agg(const unsigned short* __restrict__ y16,
                                              const int* __restrict__ row_start,
                                              const int* __restrict__ cnt,
                                              const uint2* __restrict__ rec,
                                              float* __restrict__ agg) {
    const int wid = threadIdx.x >> 6;
    const int lane = threadIdx.x & 63;
    const int n = blockIdx.x * 4 + wid;
    const int st = row_start[n];
    const int c = cnt[n];
    const int end = st + c;
    const unsigned int* y32 = (const unsigned int*)y16;

    float ax0 = 0.f, ay0 = 0.f, ax1 = 0.f, ay1 = 0.f;
    float ax2 = 0.f, ay2 = 0.f, ax3 = 0.f, ay3 = 0.f;
    int p = st;
    for (; p + 4 <= end; p += 4) {
        const uint2 r0 = rec[p];
        const uint2 r1 = rec[p + 1];
        const uint2 r2 = rec[p + 2];
        const uint2 r3 = rec[p + 3];
        const unsigned int u0 = y32[r0.x * 64 + lane];
        const unsigned int u1 = y32[r1.x * 64 + lane];
        const unsigned int u2 = y32[r2.x * 64 + lane];
        const unsigned int u3 = y32[r3.x * 64 + lane];
        const float w0 = __uint_as_float(r0.y);
        const float w1 = __uint_as_float(r1.y);
        const float w2 = __uint_as_float(r2.y);
        const float w3 = __uint_as_float(r3.y);
        ax0 = fmaf(__uint_as_float(u0 << 16), w0, ax0);
        ay0 = fmaf(__uint_as_float(u0 & 0xFFFF0000u), w0, ay0);
        ax1 = fmaf(__uint_as_float(u1 << 16), w1, ax1);
        ay1 = fmaf(__uint_as_float(u1 & 0xFFFF0000u), w1, ay1);
        ax2 = fmaf(__uint_as_float(u2 << 16), w2, ax2);
        ay2 = fmaf(__uint_as_float(u2 & 0xFFFF0000u), w2, ay2);
        ax3 = fmaf(__uint_as_float(u3 << 16), w3, ax3);
        ay3 = fmaf(__uint_as_float(u3 & 0xFFFF0000u), w3, ay3);
    }
    for (; p < end; ++p) {
        const uint2 r0 = rec[p];
        const unsigned int u0 = y32[r0.x * 64 + lane];
        const float w0 = __uint_as_float(r0.y);
        ax0 = fmaf(__uint_as_float(u0 << 16), w0, ax0);
        ay0 = fmaf(__uint_as_float(u0 & 0xFFFF0000u), w0, ay0);
    }
    const float accx = (ax0 + ax1) + (ax2 + ax3);
    const float accy = (ay0 + ay1) + (ay2 + ay3);
    const float inv = 1.0f / fmaxf((float)c, 1.0f);
    ((float2*)agg)[n * 64 + lane] = make_float2(accx * inv, accy * inv);
}

// ---------------------------------------------------------------------------
// K4 (MFMA): fused update MLP + residual + LayerNorm.
// ---------------------------------------------------------------------------
__global__ __launch_bounds__(256) void k4_update(const float* __restrict__ x,
                                                 const float* agg,
                                                 const unsigned short* __restrict__ w1t,
                                                 const float* __restrict__ b1,
                                                 const unsigned short* __restrict__ w2t,
                                                 const float* __restrict__ b2,
                                                 const float* __restrict__ lng,
                                                 const float* __restrict__ lnb,
                                                 const unsigned short* __restrict__ rest,
                                                 float* out) {
    __shared__ unsigned short A1[32 * 264];  // cat(x,agg) bf16, +8 pad
    __shared__ unsigned short A2[32 * 136];  // h1 bf16, +8 pad
    __shared__ float red_s[4][32];
    __shared__ float red_q[4][32];
    __shared__ float ln_mu[32];
    __shared__ float ln_rs[32];

    const int t = threadIdx.x;
    const int n0 = blockIdx.x * 32;
    const float4* x4 = (const float4*)x;
    const float4* agg4 = (const float4*)agg;

#pragma unroll
    for (int r = 0; r < 4; ++r) {
        const int idx = t + r * 256;
        const int node = idx >> 5, c4 = idx & 31;
        const float4 vx = x4[(n0 + node) * 32 + c4];
        const float4 va = agg4[(n0 + node) * 32 + c4];
        ushort4 px, pa;
        px.x = f2bf_(vx.x); px.y = f2bf_(vx.y); px.z = f2bf_(vx.z); px.w = f2bf_(vx.w);
        pa.x = f2bf_(va.x); pa.y = f2bf_(va.y); pa.z = f2bf_(va.z); pa.w = f2bf_(va.w);
        *(ushort4*)&A1[node * 264 + c4 * 4] = px;
        *(ushort4*)&A1[node * 264 + 128 + c4 * 4] = pa;
    }
    __syncthreads();

    const int w = t >> 6, lane = t & 63, nq = lane & 15, quad = lane >> 4;

    // ---- layer 1: [32x256] @ [256x128] ----
    f32x4 c1[2][2] = {};
#pragma unroll
    for (int ks = 0; ks < 8; ++ks) {
        const int k0 = ks * 32 + quad * 8;
        const short8 a0 = *(const short8*)&A1[(nq)*264 + k0];
        const short8 a1 = *(const short8*)&A1[(16 + nq) * 264 + k0];
        const short8 b0 = *(const short8*)&w1t[(w * 32 + nq) * 256 + k0];
        const short8 b1f = *(const short8*)&w1t[(w * 32 + 16 + nq) * 256 + k0];
        c1[0][0] = MFMA16(a0, b0, c1[0][0]);
        c1[0][1] = MFMA16(a0, b1f, c1[0][1]);
        c1[1][0] = MFMA16(a1, b0, c1[1][0]);
        c1[1][1] = MFMA16(a1, b1f, c1[1][1]);
    }
    const float b1c0 = b1[w * 32 + nq], b1c1 = b1[w * 32 + 16 + nq];
#pragma unroll
    for (int mt = 0; mt < 2; ++mt)
#pragma unroll
        for (int r = 0; r < 4; ++r) {
            const int row = mt * 16 + quad * 4 + r;
            A2[row * 136 + w * 32 + nq] = f2bf_(siluf_(c1[mt][0][r] + b1c0));
            A2[row * 136 + w * 32 + 16 + nq] = f2bf_(siluf_(c1[mt][1][r] + b1c1));
        }
    __syncthreads();

    // ---- layer 2 + residual ----
    f32x4 c2[2][2] = {};
#pragma unroll
    for (int ks = 0; ks < 4; ++ks) {
        const int k0 = ks * 32 + quad * 8;
        const short8 a0 = *(const short8*)&A2[(nq)*136 + k0];
        const short8 a1 = *(const short8*)&A2[(16 + nq) * 136 + k0];
        const short8 b0 = *(const short8*)&w2t[(w * 32 + nq) * 128 + k0];
        const short8 b1f = *(const short8*)&w2t[(w * 32 + 16 + nq) * 128 + k0];
        c2[0][0] = MFMA16(a0, b0, c2[0][0]);
        c2[0][1] = MFMA16(a0, b1f, c2[0][1]);
        c2[1][0] = MFMA16(a1, b0, c2[1][0]);
        c2[1][1] = MFMA16(a1, b1f, c2[1][1]);
    }
#pragma unroll
    for (int ks = 0; ks < 4; ++ks) {
        const int k0 = ks * 32 + quad * 8;
        const short8 a0 = *(const short8*)&A1[(nq)*264 + k0];       // x half
        const short8 a1 = *(const short8*)&A1[(16 + nq) * 264 + k0];
        const short8 b0 = *(const short8*)&rest[(w * 32 + nq) * 128 + k0];
        const short8 b1f = *(const short8*)&rest[(w * 32 + 16 + nq) * 128 + k0];
        c2[0][0] = MFMA16(a0, b0, c2[0][0]);
        c2[0][1] = MFMA16(a0, b1f, c2[0][1]);
        c2[1][0] = MFMA16(a1, b0, c2[1][0]);
        c2[1][1] = MFMA16(a1, b1f, c2[1][1]);
    }

    // ---- LayerNorm ----
    const float b2c0 = b2[w * 32 + nq], b2c1 = b2[w * 32 + 16 + nq];
    float vals[2][2][4];
#pragma unroll
    for (int mt = 0; mt < 2; ++mt)
#pragma unroll
        for (int r = 0; r < 4; ++r) {
            vals[mt][0][r] = c2[mt][0][r] + b2c0;
            vals[mt][1][r] = c2[mt][1][r] + b2c1;
        }
#pragma unroll
    for (int mt = 0; mt < 2; ++mt)
#pragma unroll
        for (int r = 0; r < 4; ++r) {
            float s = vals[mt][0][r] + vals[mt][1][r];
            float q = vals[mt][0][r] * vals[mt][0][r] + vals[mt][1][r] * vals[mt][1][r];
#pragma unroll
            for (int off = 1; off <= 8; off <<= 1) {
                s += __shfl_xor(s, off, 64);
                q += __shfl_xor(q, off, 64);
            }
            if (nq == 0) {
                const int row = mt * 16 + quad * 4 + r;
                red_s[w][row] = s;
                red_q[w][row] = q;
            }
        }
    __syncthreads();
    if (t < 32) {
        const float ts = red_s[0][t] + red_s[1][t] + red_s[2][t] + red_s[3][t];
        const float tq = red_q[0][t] + red_q[1][t] + red_q[2][t] + red_q[3][t];
        const float mu = ts * (1.0f / 128.0f);
        const float var = fmaxf(tq * (1.0f / 128.0f) - mu * mu, 0.f);
        ln_mu[t] = mu;
        ln_rs[t] = rsqrtf(var + LN_EPS);
    }
    __syncthreads();

    const float g0 = lng[w * 32 + nq], g1 = lng[w * 32 + 16 + nq];
    const float lb0 = lnb[w * 32 + nq], lb1 = lnb[w * 32 + 16 + nq];
#pragma unroll
    for (int mt = 0; mt < 2; ++mt)
#pragma unroll
        for (int r = 0; r < 4; ++r) {
            const int row = mt * 16 + quad * 4 + r;
            const float mu = ln_mu[row], rs = ln_rs[row];
            out[(n0 + row) * 128 + w * 32 + nq] = (vals[mt][0][r] - mu) * rs * g0 + lb0;
            out[(n0 + row) * 128 + w * 32 + 16 + nq] = (vals[mt][1][r] - mu) * rs * g1 + lb1;
        }
}

// ---------------------------------------------------------------------------
extern "C" void kernel_launch(void* const* d_in, const int* in_sizes, int n_in,
                              void* d_out, int out_size, void* d_ws, size_t ws_size,
                              hipStream_t stream) {
    const float* x = (const float*)d_in[0];
    const int* ei = (const int*)d_in[1];
    const float* eattr = (const float*)d_in[2];
    const float* aggW = (const float*)d_in[3];
    const float* aggb = (const float*)d_in[4];
    const float* eW1 = (const float*)d_in[5];
    const float* eb1 = (const float*)d_in[6];
    const float* eW2 = (const float*)d_in[7];
    const float* eb2 = (const float*)d_in[8];
    const float* uW1 = (const float*)d_in[9];
    const float* ub1 = (const float*)d_in[10];
    const float* uW2 = (const float*)d_in[11];
    const float* ub2 = (const float*)d_in[12];
    const float* lng = (const float*)d_in[13];
    const float* lnb = (const float*)d_in[14];
    const float* resW = (const float*)d_in[15];
    float* out = (float*)d_out;

    // workspace layout (bytes) — total ~46.3 MB (< out bytes = 51.2 MB)
    char* ws = (char*)d_ws;
    unsigned short* y16 = (unsigned short*)(ws + 0);   // 25.6 MB
    float* ew = (float*)(ws + 25600000);               // 6.4 MB
    uint2* rec = (uint2*)(ws + 32000000);              // 12.8 MB (8B records)
    int* cnt = (int*)(ws + 44800000);                  // 0.4 MB
    int* alloc = (int*)(ws + 45200000);                // 4 B
    int* rowst = (int*)(ws + 45200004);                // 0.4 MB
    int* cursor = (int*)(ws + 45600004);               // 0.4 MB -> 46,000,004
    unsigned short* w1t = (unsigned short*)(ws + 46000016);   // 65,536 B
    unsigned short* w2t = (unsigned short*)(ws + 46065552);   // 32,768 B
    unsigned short* rest = (unsigned short*)(ws + 46098320);  // 32,768 B
    unsigned short* aggt = (unsigned short*)(ws + 46131088);  // 32,768 B
    float* agg = out;  // aliased onto d_out (safe: block-local rows in K4)

    const int* src = ei;
    const int* dst = ei + N_EDGES;

    hipMemsetAsync(cnt, 0, N_NODES * 4 + 4, stream);  // cnt + alloc

    kw<<<320, 256, 0, stream>>>(uW1, uW2, resW, aggW, w1t, w2t, rest, aggt);
    k1_y<<<N_NODES / 32, 256, 0, stream>>>(x, aggt, aggb, y16);
    pe1<<<N_EDGES / 256, 256, 0, stream>>>(eattr, eW1, eb1, eW2, eb2, dst, ew, cnt);
    p2_alloc<<<(N_NODES + 255) / 256, 256, 0, stream>>>(cnt, rowst, cursor, alloc);
    p3_fill<<<N_EDGES / 256, 256, 0, stream>>>(src, dst, ew, cursor, rec);
    p4_agg<<<N_NODES / 4, 256, 0, stream>>>(y16, rowst, cnt, rec, agg);
    k4_update<<<N_NODES / 32, 256, 0, stream>>>(x, agg, w1t, ub1, w2t, ub2, lng, lnb, rest, out);
}

// Round 5
// 472.930 us; speedup vs baseline: 2.0022x; 1.1146x over previous
//
#include <hip/hip_runtime.h>
#include <math.h>

#define N_NODES 100000
#define N_EDGES 1600000
#define LN_EPS 1e-5f

// bucketed aggregation: 16 nodes per bucket
#define B_SHIFT 4
#define B_NODES 16
#define N_BUCKETS 6250           // 100000 / 16
#define B_CAP 1024               // LDS cap per bucket (mean 256, 6-sigma ~390)

typedef __attribute__((ext_vector_type(8))) short short8;
typedef __attribute__((ext_vector_type(4))) float f32x4;
#define MFMA16(a, b, c) __builtin_amdgcn_mfma_f32_16x16x32_bf16(a, b, c, 0, 0, 0)

__device__ __forceinline__ float sigmoidf_(float v) { return 1.0f / (1.0f + __expf(-v)); }
__device__ __forceinline__ float siluf_(float v) { return v * sigmoidf_(v); }

// bf16 pack (round-to-nearest-even)
__device__ __forceinline__ unsigned short f2bf_(float f) {
    unsigned int u = __float_as_uint(f);
    unsigned int rounded = u + 0x7FFF + ((u >> 16) & 1);
    return (unsigned short)(rounded >> 16);
}

// ---------------------------------------------------------------------------
// KW: convert + transpose weights to bf16 [n][k] (contiguous B-fragments).
// ---------------------------------------------------------------------------
__global__ __launch_bounds__(256) void kw(const float* __restrict__ W1,
                                          const float* __restrict__ W2,
                                          const float* __restrict__ resW,
                                          const float* __restrict__ aggW,
                                          unsigned short* __restrict__ w1t,
                                          unsigned short* __restrict__ w2t,
                                          unsigned short* __restrict__ rest,
                                          unsigned short* __restrict__ aggt) {
    const int idx = blockIdx.x * 256 + threadIdx.x;  // 0..81919
    if (idx < 32768) {
        const int n = idx >> 8, k = idx & 255;
        w1t[idx] = f2bf_(W1[k * 128 + n]);
    } else if (idx < 49152) {
        const int i = idx - 32768, n = i >> 7, k = i & 127;
        w2t[i] = f2bf_(W2[k * 128 + n]);
    } else if (idx < 65536) {
        const int i = idx - 49152, n = i >> 7, k = i & 127;
        rest[i] = f2bf_(resW[k * 128 + n]);
    } else {
        const int i = idx - 65536, n = i >> 7, k = i & 127;
        aggt[i] = f2bf_(aggW[k * 128 + n]);
    }
}

// ---------------------------------------------------------------------------
// K1 (MFMA): y16 = bf16( silu(x @ aggW + b) ).  32 nodes/block, 256 thr.
// ---------------------------------------------------------------------------
__global__ __launch_bounds__(256) void k1_y(const float* __restrict__ x,
                                            const unsigned short* __restrict__ aggt,
                                            const float* __restrict__ b,
                                            unsigned short* __restrict__ y16) {
    __shared__ unsigned short A1[32 * 136];
    __shared__ unsigned short O[32 * 136];
    const int t = threadIdx.x;
    const int n0 = blockIdx.x * 32;
    const float4* x4 = (const float4*)x;

#pragma unroll
    for (int r = 0; r < 4; ++r) {
        const int idx = t + r * 256;          // 32 nodes x 32 float4
        const int node = idx >> 5, c4 = idx & 31;
        const float4 v = x4[(n0 + node) * 32 + c4];
        ushort4 p;
        p.x = f2bf_(v.x); p.y = f2bf_(v.y); p.z = f2bf_(v.z); p.w = f2bf_(v.w);
        *(ushort4*)&A1[node * 136 + c4 * 4] = p;
    }
    __syncthreads();

    const int w = t >> 6, lane = t & 63, nq = lane & 15, quad = lane >> 4;
    f32x4 c[2][2] = {};
#pragma unroll
    for (int ks = 0; ks < 4; ++ks) {
        const int k0 = ks * 32 + quad * 8;
        const short8 a0 = *(const short8*)&A1[(nq)*136 + k0];
        const short8 a1 = *(const short8*)&A1[(16 + nq) * 136 + k0];
        const short8 b0 = *(const short8*)&aggt[(w * 32 + nq) * 128 + k0];
        const short8 b1 = *(const short8*)&aggt[(w * 32 + 16 + nq) * 128 + k0];
        c[0][0] = MFMA16(a0, b0, c[0][0]);
        c[0][1] = MFMA16(a0, b1, c[0][1]);
        c[1][0] = MFMA16(a1, b0, c[1][0]);
        c[1][1] = MFMA16(a1, b1, c[1][1]);
    }
    const float bc0 = b[w * 32 + nq], bc1 = b[w * 32 + 16 + nq];
#pragma unroll
    for (int mt = 0; mt < 2; ++mt)
#pragma unroll
        for (int r = 0; r < 4; ++r) {
            const int row = mt * 16 + quad * 4 + r;
            O[row * 136 + w * 32 + nq] = f2bf_(siluf_(c[mt][0][r] + bc0));
            O[row * 136 + w * 32 + 16 + nq] = f2bf_(siluf_(c[mt][1][r] + bc1));
        }
    __syncthreads();

#pragma unroll
    for (int r = 0; r < 2; ++r) {
        const int idx = t + r * 256;          // 32 rows x 16 chunks(16B)
        const int row = idx >> 4, c8 = idx & 15;
        const short8 v = *(const short8*)&O[row * 136 + c8 * 8];
        *(short8*)&y16[(n0 + row) * 128 + c8 * 8] = v;
    }
}

// ---------------------------------------------------------------------------
// PE1 (fused): per-edge gate MLP + BUCKET histogram (6250 buckets).
// ---------------------------------------------------------------------------
__global__ __launch_bounds__(256) void pe1(const float* __restrict__ attr,
                                           const float* __restrict__ W1,
                                           const float* __restrict__ b1,
                                           const float* __restrict__ W2,
                                           const float* __restrict__ b2,
                                           const int* __restrict__ dst,
                                           float* __restrict__ ew,
                                           int* __restrict__ bcnt) {
    __shared__ float4 W1s[128];
    __shared__ float4 W2s[32];
    __shared__ float4 b1s[32];
    const int t = threadIdx.x;
    if (t < 128) W1s[t] = ((const float4*)W1)[t];
    if (t < 32) {
        W2s[t] = ((const float4*)W2)[t];
        b1s[t] = ((const float4*)b1)[t];
    }
    __syncthreads();

    const int e = blockIdx.x * 256 + t;
    const float4 a = ((const float4*)attr)[e];
    const int d = dst[e];
    float acc = 0.f;
#pragma unroll 8
    for (int j4 = 0; j4 < 32; ++j4) {
        const float4 r0 = W1s[j4];
        const float4 r1 = W1s[32 + j4];
        const float4 r2 = W1s[64 + j4];
        const float4 r3 = W1s[96 + j4];
        const float4 bb = b1s[j4];
        const float4 w2v = W2s[j4];
        float hx = fmaf(a.x, r0.x, fmaf(a.y, r1.x, fmaf(a.z, r2.x, fmaf(a.w, r3.x, bb.x))));
        float hy = fmaf(a.x, r0.y, fmaf(a.y, r1.y, fmaf(a.z, r2.y, fmaf(a.w, r3.y, bb.y))));
        float hz = fmaf(a.x, r0.z, fmaf(a.y, r1.z, fmaf(a.z, r2.z, fmaf(a.w, r3.z, bb.z))));
        float hw = fmaf(a.x, r0.w, fmaf(a.y, r1.w, fmaf(a.z, r2.w, fmaf(a.w, r3.w, bb.w))));
        acc = fmaf(siluf_(hx), w2v.x, acc);
        acc = fmaf(siluf_(hy), w2v.y, acc);
        acc = fmaf(siluf_(hz), w2v.z, acc);
        acc = fmaf(siluf_(hw), w2v.w, acc);
    }
    ew[e] = sigmoidf_(acc + b2[0]);
    atomicAdd(&bcnt[d >> B_SHIFT], 1);
}

// ---------------------------------------------------------------------------
// P2B: unordered bucket-segment allocation (wave scan + one bump per wave)
// ---------------------------------------------------------------------------
__global__ __launch_bounds__(256) void p2b(const int* __restrict__ bcnt,
                                           int* __restrict__ bstart,
                                           int* __restrict__ bcursor,
                                           int* __restrict__ alloc) {
    const int n = blockIdx.x * 256 + threadIdx.x;
    const int lane = threadIdx.x & 63;
    const int c = (n < N_BUCKETS) ? bcnt[n] : 0;
    int s = c;
#pragma unroll
    for (int off = 1; off < 64; off <<= 1) {
        const int v = __shfl_up(s, off, 64);
        if (lane >= off) s += v;
    }
    const int total = __shfl(s, 63, 64);
    int base = 0;
    if (lane == 63) base = atomicAdd(alloc, total);
    base = __shfl(base, 63, 64);
    if (n < N_BUCKETS) {
        const int st = base + s - c;
        bstart[n] = st;
        bcursor[n] = st;
    }
}

// ---------------------------------------------------------------------------
// P3B: append packed {src | dstLocal<<27, ew} records to bucket tails.
// Appends to 6250 hot tails -> lines fill ~8 records deep (low write amp).
// ---------------------------------------------------------------------------
__global__ __launch_bounds__(256) void p3b(const int* __restrict__ src,
                                           const int* __restrict__ dst,
                                           const float* __restrict__ ew,
                                           int* __restrict__ bcursor,
                                           uint2* __restrict__ brec) {
    const int e = blockIdx.x * 256 + threadIdx.x;
    const int d = dst[e];
    const int b = d >> B_SHIFT;
    const int slot = atomicAdd(&bcursor[b], 1);
    brec[slot] = make_uint2((unsigned)src[e] | ((unsigned)(d & (B_NODES - 1)) << 27),
                            __float_as_uint(ew[e]));
}

// ---------------------------------------------------------------------------
// PB: one block per bucket. Load bucket records into LDS, 16-counter counting
// sort (LDS), then per-node gather-accumulate with records served from LDS.
// agg[n] = (1/max(deg,1)) * sum ew*y[src]  -> written into d_out (aliased).
// ---------------------------------------------------------------------------
__global__ __launch_bounds__(256) void pB(const unsigned short* __restrict__ y16,
                                          const int* __restrict__ bstart,
                                          const int* __restrict__ bcnt,
                                          const uint2* __restrict__ brec,
                                          float* __restrict__ agg) {
    __shared__ uint2 raw[B_CAP];     // 8 KB
    __shared__ uint2 srec[B_CAP];    // 8 KB
    __shared__ int hist[B_NODES];
    __shared__ int nstart[B_NODES];
    __shared__ int ncur[B_NODES];

    const int t = threadIdx.x;
    const int b = blockIdx.x;
    const int base = bstart[b];
    int c = bcnt[b];
    if (c > B_CAP) c = B_CAP;  // impossible for this input; guards LDS

    if (t < B_NODES) hist[t] = 0;
    __syncthreads();

    // phase 1: stage records + LDS histogram of dstLocal
    for (int i = t; i < c; i += 256) {
        const uint2 r = brec[base + i];
        raw[i] = r;
        atomicAdd(&hist[r.x >> 27], 1);
    }
    __syncthreads();

    // phase 2: tiny serial scan (16 entries) by thread 0
    if (t == 0) {
        int acc = 0;
#pragma unroll
        for (int d = 0; d < B_NODES; ++d) {
            nstart[d] = acc;
            ncur[d] = acc;
            acc += hist[d];
        }
    }
    __syncthreads();

    // phase 3: LDS->LDS scatter into per-node groups
    for (int i = t; i < c; i += 256) {
        const uint2 r = raw[i];
        const int slot = atomicAdd(&ncur[r.x >> 27], 1);
        srec[slot] = r;
    }
    __syncthreads();

    // phase 4: gather-accumulate. Wave w handles nodes {w, w+4, w+8, w+12}.
    const int w = t >> 6, lane = t & 63;
    const unsigned int* y32 = (const unsigned int*)y16;
#pragma unroll
    for (int rep = 0; rep < 4; ++rep) {
        const int d = w + rep * 4;
        const int st = nstart[d];
        const int cd = hist[d];
        const int end = st + cd;
        float ax0 = 0.f, ay0 = 0.f, ax1 = 0.f, ay1 = 0.f;
        float ax2 = 0.f, ay2 = 0.f, ax3 = 0.f, ay3 = 0.f;
        int p = st;
        for (; p + 4 <= end; p += 4) {
            const uint2 r0 = srec[p];
            const uint2 r1 = srec[p + 1];
            const uint2 r2 = srec[p + 2];
            const uint2 r3 = srec[p + 3];
            const unsigned int u0 = y32[(r0.x & 0x7FFFFFFu) * 64 + lane];
            const unsigned int u1 = y32[(r1.x & 0x7FFFFFFu) * 64 + lane];
            const unsigned int u2 = y32[(r2.x & 0x7FFFFFFu) * 64 + lane];
            const unsigned int u3 = y32[(r3.x & 0x7FFFFFFu) * 64 + lane];
            const float w0 = __uint_as_float(r0.y);
            const float w1 = __uint_as_float(r1.y);
            const float w2 = __uint_as_float(r2.y);
            const float w3 = __uint_as_float(r3.y);
            ax0 = fmaf(__uint_as_float(u0 << 16), w0, ax0);
            ay0 = fmaf(__uint_as_float(u0 & 0xFFFF0000u), w0, ay0);
            ax1 = fmaf(__uint_as_float(u1 << 16), w1, ax1);
            ay1 = fmaf(__uint_as_float(u1 & 0xFFFF0000u), w1, ay1);
            ax2 = fmaf(__uint_as_float(u2 << 16), w2, ax2);
            ay2 = fmaf(__uint_as_float(u2 & 0xFFFF0000u), w2, ay2);
            ax3 = fmaf(__uint_as_float(u3 << 16), w3, ax3);
            ay3 = fmaf(__uint_as_float(u3 & 0xFFFF0000u), w3, ay3);
        }
        for (; p < end; ++p) {
            const uint2 r0 = srec[p];
            const unsigned int u0 = y32[(r0.x & 0x7FFFFFFu) * 64 + lane];
            const float w0 = __uint_as_float(r0.y);
            ax0 = fmaf(__uint_as_float(u0 << 16), w0, ax0);
            ay0 = fmaf(__uint_as_float(u0 & 0xFFFF0000u), w0, ay0);
        }
        const float accx = (ax0 + ax1) + (ax2 + ax3);
        const float accy = (ay0 + ay1) + (ay2 + ay3);
        const float inv = 1.0f / fmaxf((float)cd, 1.0f);
        const int n = b * B_NODES + d;
        ((float2*)agg)[n * 64 + lane] = make_float2(accx * inv, accy * inv);
    }
}

// ---------------------------------------------------------------------------
// K4 (MFMA): fused update MLP + residual + LayerNorm.
// ---------------------------------------------------------------------------
__global__ __launch_bounds__(256) void k4_update(const float* __restrict__ x,
                                                 const float* agg,
                                                 const unsigned short* __restrict__ w1t,
                                                 const float* __restrict__ b1,
                                                 const unsigned short* __restrict__ w2t,
                                                 const float* __restrict__ b2,
                                                 const float* __restrict__ lng,
                                                 const float* __restrict__ lnb,
                                                 const unsigned short* __restrict__ rest,
                                                 float* out) {
    __shared__ unsigned short A1[32 * 264];  // cat(x,agg) bf16, +8 pad
    __shared__ unsigned short A2[32 * 136];  // h1 bf16, +8 pad
    __shared__ float red_s[4][32];
    __shared__ float red_q[4][32];
    __shared__ float ln_mu[32];
    __shared__ float ln_rs[32];

    const int t = threadIdx.x;
    const int n0 = blockIdx.x * 32;
    const float4* x4 = (const float4*)x;
    const float4* agg4 = (const float4*)agg;

#pragma unroll
    for (int r = 0; r < 4; ++r) {
        const int idx = t + r * 256;
        const int node = idx >> 5, c4 = idx & 31;
        const float4 vx = x4[(n0 + node) * 32 + c4];
        const float4 va = agg4[(n0 + node) * 32 + c4];
        ushort4 px, pa;
        px.x = f2bf_(vx.x); px.y = f2bf_(vx.y); px.z = f2bf_(vx.z); px.w = f2bf_(vx.w);
        pa.x = f2bf_(va.x); pa.y = f2bf_(va.y); pa.z = f2bf_(va.z); pa.w = f2bf_(va.w);
        *(ushort4*)&A1[node * 264 + c4 * 4] = px;
        *(ushort4*)&A1[node * 264 + 128 + c4 * 4] = pa;
    }
    __syncthreads();

    const int w = t >> 6, lane = t & 63, nq = lane & 15, quad = lane >> 4;

    // ---- layer 1: [32x256] @ [256x128] ----
    f32x4 c1[2][2] = {};
#pragma unroll
    for (int ks = 0; ks < 8; ++ks) {
        const int k0 = ks * 32 + quad * 8;
        const short8 a0 = *(const short8*)&A1[(nq)*264 + k0];
        const short8 a1 = *(const short8*)&A1[(16 + nq) * 264 + k0];
        const short8 b0 = *(const short8*)&w1t[(w * 32 + nq) * 256 + k0];
        const short8 b1f = *(const short8*)&w1t[(w * 32 + 16 + nq) * 256 + k0];
        c1[0][0] = MFMA16(a0, b0, c1[0][0]);
        c1[0][1] = MFMA16(a0, b1f, c1[0][1]);
        c1[1][0] = MFMA16(a1, b0, c1[1][0]);
        c1[1][1] = MFMA16(a1, b1f, c1[1][1]);
    }
    const float b1c0 = b1[w * 32 + nq], b1c1 = b1[w * 32 + 16 + nq];
#pragma unroll
    for (int mt = 0; mt < 2; ++mt)
#pragma unroll
        for (int r = 0; r < 4; ++r) {
            const int row = mt * 16 + quad * 4 + r;
            A2[row * 136 + w * 32 + nq] = f2bf_(siluf_(c1[mt][0][r] + b1c0));
            A2[row * 136 + w * 32 + 16 + nq] = f2bf_(siluf_(c1[mt][1][r] + b1c1));
        }
    __syncthreads();

    // ---- layer 2 + residual ----
    f32x4 c2[2][2] = {};
#pragma unroll
    for (int ks = 0; ks < 4; ++ks) {
        const int k0 = ks * 32 + quad * 8;
        const short8 a0 = *(const short8*)&A2[(nq)*136 + k0];
        const short8 a1 = *(const short8*)&A2[(16 + nq) * 136 + k0];
        const short8 b0 = *(const short8*)&w2t[(w * 32 + nq) * 128 + k0];
        const short8 b1f = *(const short8*)&w2t[(w * 32 + 16 + nq) * 128 + k0];
        c2[0][0] = MFMA16(a0, b0, c2[0][0]);
        c2[0][1] = MFMA16(a0, b1f, c2[0][1]);
        c2[1][0] = MFMA16(a1, b0, c2[1][0]);
        c2[1][1] = MFMA16(a1, b1f, c2[1][1]);
    }
#pragma unroll
    for (int ks = 0; ks < 4; ++ks) {
        const int k0 = ks * 32 + quad * 8;
        const short8 a0 = *(const short8*)&A1[(nq)*264 + k0];       // x half
        const short8 a1 = *(const short8*)&A1[(16 + nq) * 264 + k0];
        const short8 b0 = *(const short8*)&rest[(w * 32 + nq) * 128 + k0];
        const short8 b1f = *(const short8*)&rest[(w * 32 + 16 + nq) * 128 + k0];
        c2[0][0] = MFMA16(a0, b0, c2[0][0]);
        c2[0][1] = MFMA16(a0, b1f, c2[0][1]);
        c2[1][0] = MFMA16(a1, b0, c2[1][0]);
        c2[1][1] = MFMA16(a1, b1f, c2[1][1]);
    }

    // ---- LayerNorm ----
    const float b2c0 = b2[w * 32 + nq], b2c1 = b2[w * 32 + 16 + nq];
    float vals[2][2][4];
#pragma unroll
    for (int mt = 0; mt < 2; ++mt)
#pragma unroll
        for (int r = 0; r < 4; ++r) {
            vals[mt][0][r] = c2[mt][0][r] + b2c0;
            vals[mt][1][r] = c2[mt][1][r] + b2c1;
        }
#pragma unroll
    for (int mt = 0; mt < 2; ++mt)
#pragma unroll
        for (int r = 0; r < 4; ++r) {
            float s = vals[mt][0][r] + vals[mt][1][r];
            float q = vals[mt][0][r] * vals[mt][0][r] + vals[mt][1][r] * vals[mt][1][r];
#pragma unroll
            for (int off = 1; off <= 8; off <<= 1) {
                s += __shfl_xor(s, off, 64);
                q += __shfl_xor(q, off, 64);
            }
            if (nq == 0) {
                const int row = mt * 16 + quad * 4 + r;
                red_s[w][row] = s;
                red_q[w][row] = q;
            }
        }
    __syncthreads();
    if (t < 32) {
        const float ts = red_s[0][t] + red_s[1][t] + red_s[2][t] + red_s[3][t];
        const float tq = red_q[0][t] + red_q[1][t] + red_q[2][t] + red_q[3][t];
        const float mu = ts * (1.0f / 128.0f);
        const float var = fmaxf(tq * (1.0f / 128.0f) - mu * mu, 0.f);
        ln_mu[t] = mu;
        ln_rs[t] = rsqrtf(var + LN_EPS);
    }
    __syncthreads();

    const float g0 = lng[w * 32 + nq], g1 = lng[w * 32 + 16 + nq];
    const float lb0 = lnb[w * 32 + nq], lb1 = lnb[w * 32 + 16 + nq];
#pragma unroll
    for (int mt = 0; mt < 2; ++mt)
#pragma unroll
        for (int r = 0; r < 4; ++r) {
            const int row = mt * 16 + quad * 4 + r;
            const float mu = ln_mu[row], rs = ln_rs[row];
            out[(n0 + row) * 128 + w * 32 + nq] = (vals[mt][0][r] - mu) * rs * g0 + lb0;
            out[(n0 + row) * 128 + w * 32 + 16 + nq] = (vals[mt][1][r] - mu) * rs * g1 + lb1;
        }
}

// ---------------------------------------------------------------------------
extern "C" void kernel_launch(void* const* d_in, const int* in_sizes, int n_in,
                              void* d_out, int out_size, void* d_ws, size_t ws_size,
                              hipStream_t stream) {
    const float* x = (const float*)d_in[0];
    const int* ei = (const int*)d_in[1];
    const float* eattr = (const float*)d_in[2];
    const float* aggW = (const float*)d_in[3];
    const float* aggb = (const float*)d_in[4];
    const float* eW1 = (const float*)d_in[5];
    const float* eb1 = (const float*)d_in[6];
    const float* eW2 = (const float*)d_in[7];
    const float* eb2 = (const float*)d_in[8];
    const float* uW1 = (const float*)d_in[9];
    const float* ub1 = (const float*)d_in[10];
    const float* uW2 = (const float*)d_in[11];
    const float* ub2 = (const float*)d_in[12];
    const float* lng = (const float*)d_in[13];
    const float* lnb = (const float*)d_in[14];
    const float* resW = (const float*)d_in[15];
    float* out = (float*)d_out;

    // workspace layout (bytes) — total ~45.0 MB (< out bytes = 51.2 MB)
    char* ws = (char*)d_ws;
    unsigned short* y16 = (unsigned short*)(ws + 0);   // 25.6 MB
    float* ew = (float*)(ws + 25600000);               // 6.4 MB
    uint2* brec = (uint2*)(ws + 32000000);             // 12.8 MB
    int* bcnt = (int*)(ws + 44800000);                 // 25,000 B
    int* alloc = (int*)(ws + 44825000);                // 4 B (adjacent: one memset)
    int* bstart = (int*)(ws + 44825004);               // 25,000 B
    int* bcursor = (int*)(ws + 44850004);              // 25,000 B
    unsigned short* w1t = (unsigned short*)(ws + 44875008);   // 65,536 B (16-aligned)
    unsigned short* w2t = (unsigned short*)(ws + 44940544);   // 32,768 B
    unsigned short* rest = (unsigned short*)(ws + 44973312);  // 32,768 B
    unsigned short* aggt = (unsigned short*)(ws + 45006080);  // 32,768 B -> 45,038,848
    float* agg = out;  // aliased onto d_out (safe: block-local rows in K4)

    const int* src = ei;
    const int* dst = ei + N_EDGES;

    hipMemsetAsync(bcnt, 0, N_BUCKETS * 4 + 4, stream);  // bcnt + alloc

    kw<<<320, 256, 0, stream>>>(uW1, uW2, resW, aggW, w1t, w2t, rest, aggt);
    k1_y<<<N_NODES / 32, 256, 0, stream>>>(x, aggt, aggb, y16);
    pe1<<<N_EDGES / 256, 256, 0, stream>>>(eattr, eW1, eb1, eW2, eb2, dst, ew, bcnt);
    p2b<<<(N_BUCKETS + 255) / 256, 256, 0, stream>>>(bcnt, bstart, bcursor, alloc);
    p3b<<<N_EDGES / 256, 256, 0, stream>>>(src, dst, ew, bcursor, brec);
    pB<<<N_BUCKETS, 256, 0, stream>>>(y16, bstart, bcnt, brec, agg);
    k4_update<<<N_NODES / 32, 256, 0, stream>>>(x, agg, w1t, ub1, w2t, ub2, lng, lnb, rest, out);
}

// Round 6
// 449.482 us; speedup vs baseline: 2.1066x; 1.0522x over previous
//
#include <hip/hip_runtime.h>
#include <math.h>

#define N_NODES 100000
#define N_EDGES 1600000
#define LN_EPS 1e-5f

// bucketed aggregation: 16 nodes per bucket
#define B_SHIFT 4
#define B_NODES 16
#define N_BUCKETS 6250           // 100000 / 16
#define B_CAP 1024               // LDS cap per bucket (mean 256)

typedef __attribute__((ext_vector_type(8))) short short8;
typedef __attribute__((ext_vector_type(4))) float f32x4;
#define MFMA16(a, b, c) __builtin_amdgcn_mfma_f32_16x16x32_bf16(a, b, c, 0, 0, 0)

#define LOG2E 1.442695040888963f

#if __has_builtin(__builtin_amdgcn_exp2f) && __has_builtin(__builtin_amdgcn_rcpf)
__device__ __forceinline__ float sigmoidf_(float v) {
    return __builtin_amdgcn_rcpf(1.0f + __builtin_amdgcn_exp2f(-LOG2E * v));
}
#else
__device__ __forceinline__ float sigmoidf_(float v) { return 1.0f / (1.0f + __expf(-v)); }
#endif
__device__ __forceinline__ float siluf_(float v) { return v * sigmoidf_(v); }

// bf16 pack (round-to-nearest-even)
__device__ __forceinline__ unsigned short f2bf_(float f) {
    unsigned int u = __float_as_uint(f);
    unsigned int rounded = u + 0x7FFF + ((u >> 16) & 1);
    return (unsigned short)(rounded >> 16);
}

// ---------------------------------------------------------------------------
// KW: convert + transpose weights to bf16 [n][k] (contiguous B-fragments).
// ---------------------------------------------------------------------------
__global__ __launch_bounds__(256) void kw(const float* __restrict__ W1,
                                          const float* __restrict__ W2,
                                          const float* __restrict__ resW,
                                          const float* __restrict__ aggW,
                                          unsigned short* __restrict__ w1t,
                                          unsigned short* __restrict__ w2t,
                                          unsigned short* __restrict__ rest,
                                          unsigned short* __restrict__ aggt) {
    const int idx = blockIdx.x * 256 + threadIdx.x;  // 0..81919
    if (idx < 32768) {
        const int n = idx >> 8, k = idx & 255;
        w1t[idx] = f2bf_(W1[k * 128 + n]);
    } else if (idx < 49152) {
        const int i = idx - 32768, n = i >> 7, k = i & 127;
        w2t[i] = f2bf_(W2[k * 128 + n]);
    } else if (idx < 65536) {
        const int i = idx - 49152, n = i >> 7, k = i & 127;
        rest[i] = f2bf_(resW[k * 128 + n]);
    } else {
        const int i = idx - 65536, n = i >> 7, k = i & 127;
        aggt[i] = f2bf_(aggW[k * 128 + n]);
    }
}

// ---------------------------------------------------------------------------
// K1 (MFMA): y16 = bf16( silu(x @ aggW + b) ).  32 nodes/block, 256 thr.
// ---------------------------------------------------------------------------
__global__ __launch_bounds__(256) void k1_y(const float* __restrict__ x,
                                            const unsigned short* __restrict__ aggt,
                                            const float* __restrict__ b,
                                            unsigned short* __restrict__ y16) {
    __shared__ unsigned short A1[32 * 136];
    __shared__ unsigned short O[32 * 136];
    const int t = threadIdx.x;
    const int n0 = blockIdx.x * 32;
    const float4* x4 = (const float4*)x;

#pragma unroll
    for (int r = 0; r < 4; ++r) {
        const int idx = t + r * 256;          // 32 nodes x 32 float4
        const int node = idx >> 5, c4 = idx & 31;
        const float4 v = x4[(n0 + node) * 32 + c4];
        ushort4 p;
        p.x = f2bf_(v.x); p.y = f2bf_(v.y); p.z = f2bf_(v.z); p.w = f2bf_(v.w);
        *(ushort4*)&A1[node * 136 + c4 * 4] = p;
    }
    __syncthreads();

    const int w = t >> 6, lane = t & 63, nq = lane & 15, quad = lane >> 4;
    f32x4 c[2][2] = {};
#pragma unroll
    for (int ks = 0; ks < 4; ++ks) {
        const int k0 = ks * 32 + quad * 8;
        const short8 a0 = *(const short8*)&A1[(nq)*136 + k0];
        const short8 a1 = *(const short8*)&A1[(16 + nq) * 136 + k0];
        const short8 b0 = *(const short8*)&aggt[(w * 32 + nq) * 128 + k0];
        const short8 b1 = *(const short8*)&aggt[(w * 32 + 16 + nq) * 128 + k0];
        c[0][0] = MFMA16(a0, b0, c[0][0]);
        c[0][1] = MFMA16(a0, b1, c[0][1]);
        c[1][0] = MFMA16(a1, b0, c[1][0]);
        c[1][1] = MFMA16(a1, b1, c[1][1]);
    }
    const float bc0 = b[w * 32 + nq], bc1 = b[w * 32 + 16 + nq];
#pragma unroll
    for (int mt = 0; mt < 2; ++mt)
#pragma unroll
        for (int r = 0; r < 4; ++r) {
            const int row = mt * 16 + quad * 4 + r;
            O[row * 136 + w * 32 + nq] = f2bf_(siluf_(c[mt][0][r] + bc0));
            O[row * 136 + w * 32 + 16 + nq] = f2bf_(siluf_(c[mt][1][r] + bc1));
        }
    __syncthreads();

#pragma unroll
    for (int r = 0; r < 2; ++r) {
        const int idx = t + r * 256;          // 32 rows x 16 chunks(16B)
        const int row = idx >> 4, c8 = idx & 15;
        const short8 v = *(const short8*)&O[row * 136 + c8 * 8];
        *(short8*)&y16[(n0 + row) * 128 + c8 * 8] = v;
    }
}

// ---------------------------------------------------------------------------
// PE0: bucket histogram only (4 edges/thread, uint4 coalesced reads).
// ---------------------------------------------------------------------------
__global__ __launch_bounds__(256) void pe0(const int* __restrict__ dst,
                                           int* __restrict__ bcnt) {
    const int i = blockIdx.x * 256 + threadIdx.x;   // i < E/4
    const uint4 d = ((const uint4*)dst)[i];
    atomicAdd(&bcnt[d.x >> B_SHIFT], 1);
    atomicAdd(&bcnt[d.y >> B_SHIFT], 1);
    atomicAdd(&bcnt[d.z >> B_SHIFT], 1);
    atomicAdd(&bcnt[d.w >> B_SHIFT], 1);
}

// ---------------------------------------------------------------------------
// P2B: unordered bucket-segment allocation (wave scan + one bump per wave)
// ---------------------------------------------------------------------------
__global__ __launch_bounds__(256) void p2b(const int* __restrict__ bcnt,
                                           int* __restrict__ bstart,
                                           int* __restrict__ bcursor,
                                           int* __restrict__ alloc) {
    const int n = blockIdx.x * 256 + threadIdx.x;
    const int lane = threadIdx.x & 63;
    const int c = (n < N_BUCKETS) ? bcnt[n] : 0;
    int s = c;
#pragma unroll
    for (int off = 1; off < 64; off <<= 1) {
        const int v = __shfl_up(s, off, 64);
        if (lane >= off) s += v;
    }
    const int total = __shfl(s, 63, 64);
    int base = 0;
    if (lane == 63) base = atomicAdd(alloc, total);
    base = __shfl(base, 63, 64);
    if (n < N_BUCKETS) {
        const int st = base + s - c;
        bstart[n] = st;
        bcursor[n] = st;
    }
}

// ---------------------------------------------------------------------------
// P3G (fused gate + scatter): per-edge gate MLP (native exp2/rcp silu) and
// direct append of {src | dstLocal<<27, ew} to the dst bucket tail.
// ---------------------------------------------------------------------------
__global__ __launch_bounds__(256) void p3g(const float* __restrict__ attr,
                                           const float* __restrict__ W1,
                                           const float* __restrict__ b1,
                                           const float* __restrict__ W2,
                                           const float* __restrict__ b2,
                                           const int* __restrict__ src,
                                           const int* __restrict__ dst,
                                           int* __restrict__ bcursor,
                                           uint2* __restrict__ brec) {
    __shared__ float4 W1s[128];
    __shared__ float4 W2s[32];
    __shared__ float4 b1s[32];
    const int t = threadIdx.x;
    if (t < 128) W1s[t] = ((const float4*)W1)[t];
    if (t < 32) {
        W2s[t] = ((const float4*)W2)[t];
        b1s[t] = ((const float4*)b1)[t];
    }
    __syncthreads();

    const int e = blockIdx.x * 256 + t;
    const float4 a = ((const float4*)attr)[e];
    const int s_ = src[e];
    const int d = dst[e];
    float acc = 0.f;
#pragma unroll 8
    for (int j4 = 0; j4 < 32; ++j4) {
        const float4 r0 = W1s[j4];
        const float4 r1 = W1s[32 + j4];
        const float4 r2 = W1s[64 + j4];
        const float4 r3 = W1s[96 + j4];
        const float4 bb = b1s[j4];
        const float4 w2v = W2s[j4];
        float hx = fmaf(a.x, r0.x, fmaf(a.y, r1.x, fmaf(a.z, r2.x, fmaf(a.w, r3.x, bb.x))));
        float hy = fmaf(a.x, r0.y, fmaf(a.y, r1.y, fmaf(a.z, r2.y, fmaf(a.w, r3.y, bb.y))));
        float hz = fmaf(a.x, r0.z, fmaf(a.y, r1.z, fmaf(a.z, r2.z, fmaf(a.w, r3.z, bb.z))));
        float hw = fmaf(a.x, r0.w, fmaf(a.y, r1.w, fmaf(a.z, r2.w, fmaf(a.w, r3.w, bb.w))));
        acc = fmaf(siluf_(hx), w2v.x, acc);
        acc = fmaf(siluf_(hy), w2v.y, acc);
        acc = fmaf(siluf_(hz), w2v.z, acc);
        acc = fmaf(siluf_(hw), w2v.w, acc);
    }
    const float ew = sigmoidf_(acc + b2[0]);
    const int b = d >> B_SHIFT;
    const int slot = atomicAdd(&bcursor[b], 1);
    brec[slot] = make_uint2((unsigned)s_ | ((unsigned)(d & (B_NODES - 1)) << 27),
                            __float_as_uint(ew));
}

// ---------------------------------------------------------------------------
// PB: one block per bucket. LDS counting-sort by dstLocal, then per-node
// gather-accumulate (records from LDS). agg -> d_out (aliased).
// ---------------------------------------------------------------------------
__global__ __launch_bounds__(256) void pB(const unsigned short* __restrict__ y16,
                                          const int* __restrict__ bstart,
                                          const int* __restrict__ bcnt,
                                          const uint2* __restrict__ brec,
                                          float* __restrict__ agg) {
    __shared__ uint2 raw[B_CAP];     // 8 KB
    __shared__ uint2 srec[B_CAP];    // 8 KB
    __shared__ int hist[B_NODES];
    __shared__ int nstart[B_NODES];
    __shared__ int ncur[B_NODES];

    const int t = threadIdx.x;
    const int b = blockIdx.x;
    const int base = bstart[b];
    int c = bcnt[b];
    if (c > B_CAP) c = B_CAP;  // guards LDS (unreachable for this input)

    if (t < B_NODES) hist[t] = 0;
    __syncthreads();

    for (int i = t; i < c; i += 256) {
        const uint2 r = brec[base + i];
        raw[i] = r;
        atomicAdd(&hist[r.x >> 27], 1);
    }
    __syncthreads();

    if (t == 0) {
        int acc = 0;
#pragma unroll
        for (int d = 0; d < B_NODES; ++d) {
            nstart[d] = acc;
            ncur[d] = acc;
            acc += hist[d];
        }
    }
    __syncthreads();

    for (int i = t; i < c; i += 256) {
        const uint2 r = raw[i];
        const int slot = atomicAdd(&ncur[r.x >> 27], 1);
        srec[slot] = r;
    }
    __syncthreads();

    const int w = t >> 6, lane = t & 63;
    const unsigned int* y32 = (const unsigned int*)y16;
#pragma unroll
    for (int rep = 0; rep < 4; ++rep) {
        const int d = w + rep * 4;
        const int st = nstart[d];
        const int cd = hist[d];
        const int end = st + cd;
        float ax0 = 0.f, ay0 = 0.f, ax1 = 0.f, ay1 = 0.f;
        float ax2 = 0.f, ay2 = 0.f, ax3 = 0.f, ay3 = 0.f;
        int p = st;
        for (; p + 4 <= end; p += 4) {
            const uint2 r0 = srec[p];
            const uint2 r1 = srec[p + 1];
            const uint2 r2 = srec[p + 2];
            const uint2 r3 = srec[p + 3];
            const unsigned int u0 = y32[(r0.x & 0x7FFFFFFu) * 64 + lane];
            const unsigned int u1 = y32[(r1.x & 0x7FFFFFFu) * 64 + lane];
            const unsigned int u2 = y32[(r2.x & 0x7FFFFFFu) * 64 + lane];
            const unsigned int u3 = y32[(r3.x & 0x7FFFFFFu) * 64 + lane];
            const float w0 = __uint_as_float(r0.y);
            const float w1 = __uint_as_float(r1.y);
            const float w2 = __uint_as_float(r2.y);
            const float w3 = __uint_as_float(r3.y);
            ax0 = fmaf(__uint_as_float(u0 << 16), w0, ax0);
            ay0 = fmaf(__uint_as_float(u0 & 0xFFFF0000u), w0, ay0);
            ax1 = fmaf(__uint_as_float(u1 << 16), w1, ax1);
            ay1 = fmaf(__uint_as_float(u1 & 0xFFFF0000u), w1, ay1);
            ax2 = fmaf(__uint_as_float(u2 << 16), w2, ax2);
            ay2 = fmaf(__uint_as_float(u2 & 0xFFFF0000u), w2, ay2);
            ax3 = fmaf(__uint_as_float(u3 << 16), w3, ax3);
            ay3 = fmaf(__uint_as_float(u3 & 0xFFFF0000u), w3, ay3);
        }
        for (; p < end; ++p) {
            const uint2 r0 = srec[p];
            const unsigned int u0 = y32[(r0.x & 0x7FFFFFFu) * 64 + lane];
            const float w0 = __uint_as_float(r0.y);
            ax0 = fmaf(__uint_as_float(u0 << 16), w0, ax0);
            ay0 = fmaf(__uint_as_float(u0 & 0xFFFF0000u), w0, ay0);
        }
        const float accx = (ax0 + ax1) + (ax2 + ax3);
        const float accy = (ay0 + ay1) + (ay2 + ay3);
        const float inv = 1.0f / fmaxf((float)cd, 1.0f);
        const int n = b * B_NODES + d;
        ((float2*)agg)[n * 64 + lane] = make_float2(accx * inv, accy * inv);
    }
}

// ---------------------------------------------------------------------------
// K4 (MFMA): fused update MLP + residual + LayerNorm.
// ---------------------------------------------------------------------------
__global__ __launch_bounds__(256) void k4_update(const float* __restrict__ x,
                                                 const float* agg,
                                                 const unsigned short* __restrict__ w1t,
                                                 const float* __restrict__ b1,
                                                 const unsigned short* __restrict__ w2t,
                                                 const float* __restrict__ b2,
                                                 const float* __restrict__ lng,
                                                 const float* __restrict__ lnb,
                                                 const unsigned short* __restrict__ rest,
                                                 float* out) {
    __shared__ unsigned short A1[32 * 264];  // cat(x,agg) bf16, +8 pad
    __shared__ unsigned short A2[32 * 136];  // h1 bf16, +8 pad
    __shared__ float red_s[4][32];
    __shared__ float red_q[4][32];
    __shared__ float ln_mu[32];
    __shared__ float ln_rs[32];

    const int t = threadIdx.x;
    const int n0 = blockIdx.x * 32;
    const float4* x4 = (const float4*)x;
    const float4* agg4 = (const float4*)agg;

#pragma unroll
    for (int r = 0; r < 4; ++r) {
        const int idx = t + r * 256;
        const int node = idx >> 5, c4 = idx & 31;
        const float4 vx = x4[(n0 + node) * 32 + c4];
        const float4 va = agg4[(n0 + node) * 32 + c4];
        ushort4 px, pa;
        px.x = f2bf_(vx.x); px.y = f2bf_(vx.y); px.z = f2bf_(vx.z); px.w = f2bf_(vx.w);
        pa.x = f2bf_(va.x); pa.y = f2bf_(va.y); pa.z = f2bf_(va.z); pa.w = f2bf_(va.w);
        *(ushort4*)&A1[node * 264 + c4 * 4] = px;
        *(ushort4*)&A1[node * 264 + 128 + c4 * 4] = pa;
    }
    __syncthreads();

    const int w = t >> 6, lane = t & 63, nq = lane & 15, quad = lane >> 4;

    // ---- layer 1: [32x256] @ [256x128] ----
    f32x4 c1[2][2] = {};
#pragma unroll
    for (int ks = 0; ks < 8; ++ks) {
        const int k0 = ks * 32 + quad * 8;
        const short8 a0 = *(const short8*)&A1[(nq)*264 + k0];
        const short8 a1 = *(const short8*)&A1[(16 + nq) * 264 + k0];
        const short8 b0 = *(const short8*)&w1t[(w * 32 + nq) * 256 + k0];
        const short8 b1f = *(const short8*)&w1t[(w * 32 + 16 + nq) * 256 + k0];
        c1[0][0] = MFMA16(a0, b0, c1[0][0]);
        c1[0][1] = MFMA16(a0, b1f, c1[0][1]);
        c1[1][0] = MFMA16(a1, b0, c1[1][0]);
        c1[1][1] = MFMA16(a1, b1f, c1[1][1]);
    }
    const float b1c0 = b1[w * 32 + nq], b1c1 = b1[w * 32 + 16 + nq];
#pragma unroll
    for (int mt = 0; mt < 2; ++mt)
#pragma unroll
        for (int r = 0; r < 4; ++r) {
            const int row = mt * 16 + quad * 4 + r;
            A2[row * 136 + w * 32 + nq] = f2bf_(siluf_(c1[mt][0][r] + b1c0));
            A2[row * 136 + w * 32 + 16 + nq] = f2bf_(siluf_(c1[mt][1][r] + b1c1));
        }
    __syncthreads();

    // ---- layer 2 + residual ----
    f32x4 c2[2][2] = {};
#pragma unroll
    for (int ks = 0; ks < 4; ++ks) {
        const int k0 = ks * 32 + quad * 8;
        const short8 a0 = *(const short8*)&A2[(nq)*136 + k0];
        const short8 a1 = *(const short8*)&A2[(16 + nq) * 136 + k0];
        const short8 b0 = *(const short8*)&w2t[(w * 32 + nq) * 128 + k0];
        const short8 b1f = *(const short8*)&w2t[(w * 32 + 16 + nq) * 128 + k0];
        c2[0][0] = MFMA16(a0, b0, c2[0][0]);
        c2[0][1] = MFMA16(a0, b1f, c2[0][1]);
        c2[1][0] = MFMA16(a1, b0, c2[1][0]);
        c2[1][1] = MFMA16(a1, b1f, c2[1][1]);
    }
#pragma unroll
    for (int ks = 0; ks < 4; ++ks) {
        const int k0 = ks * 32 + quad * 8;
        const short8 a0 = *(const short8*)&A1[(nq)*264 + k0];       // x half
        const short8 a1 = *(const short8*)&A1[(16 + nq) * 264 + k0];
        const short8 b0 = *(const short8*)&rest[(w * 32 + nq) * 128 + k0];
        const short8 b1f = *(const short8*)&rest[(w * 32 + 16 + nq) * 128 + k0];
        c2[0][0] = MFMA16(a0, b0, c2[0][0]);
        c2[0][1] = MFMA16(a0, b1f, c2[0][1]);
        c2[1][0] = MFMA16(a1, b0, c2[1][0]);
        c2[1][1] = MFMA16(a1, b1f, c2[1][1]);
    }

    // ---- LayerNorm ----
    const float b2c0 = b2[w * 32 + nq], b2c1 = b2[w * 32 + 16 + nq];
    float vals[2][2][4];
#pragma unroll
    for (int mt = 0; mt < 2; ++mt)
#pragma unroll
        for (int r = 0; r < 4; ++r) {
            vals[mt][0][r] = c2[mt][0][r] + b2c0;
            vals[mt][1][r] = c2[mt][1][r] + b2c1;
        }
#pragma unroll
    for (int mt = 0; mt < 2; ++mt)
#pragma unroll
        for (int r = 0; r < 4; ++r) {
            float s = vals[mt][0][r] + vals[mt][1][r];
            float q = vals[mt][0][r] * vals[mt][0][r] + vals[mt][1][r] * vals[mt][1][r];
#pragma unroll
            for (int off = 1; off <= 8; off <<= 1) {
                s += __shfl_xor(s, off, 64);
                q += __shfl_xor(q, off, 64);
            }
            if (nq == 0) {
                const int row = mt * 16 + quad * 4 + r;
                red_s[w][row] = s;
                red_q[w][row] = q;
            }
        }
    __syncthreads();
    if (t < 32) {
        const float ts = red_s[0][t] + red_s[1][t] + red_s[2][t] + red_s[3][t];
        const float tq = red_q[0][t] + red_q[1][t] + red_q[2][t] + red_q[3][t];
        const float mu = ts * (1.0f / 128.0f);
        const float var = fmaxf(tq * (1.0f / 128.0f) - mu * mu, 0.f);
        ln_mu[t] = mu;
        ln_rs[t] = rsqrtf(var + LN_EPS);
    }
    __syncthreads();

    const float g0 = lng[w * 32 + nq], g1 = lng[w * 32 + 16 + nq];
    const float lb0 = lnb[w * 32 + nq], lb1 = lnb[w * 32 + 16 + nq];
#pragma unroll
    for (int mt = 0; mt < 2; ++mt)
#pragma unroll
        for (int r = 0; r < 4; ++r) {
            const int row = mt * 16 + quad * 4 + r;
            const float mu = ln_mu[row], rs = ln_rs[row];
            out[(n0 + row) * 128 + w * 32 + nq] = (vals[mt][0][r] - mu) * rs * g0 + lb0;
            out[(n0 + row) * 128 + w * 32 + 16 + nq] = (vals[mt][1][r] - mu) * rs * g1 + lb1;
        }
}

// ---------------------------------------------------------------------------
extern "C" void kernel_launch(void* const* d_in, const int* in_sizes, int n_in,
                              void* d_out, int out_size, void* d_ws, size_t ws_size,
                              hipStream_t stream) {
    const float* x = (const float*)d_in[0];
    const int* ei = (const int*)d_in[1];
    const float* eattr = (const float*)d_in[2];
    const float* aggW = (const float*)d_in[3];
    const float* aggb = (const float*)d_in[4];
    const float* eW1 = (const float*)d_in[5];
    const float* eb1 = (const float*)d_in[6];
    const float* eW2 = (const float*)d_in[7];
    const float* eb2 = (const float*)d_in[8];
    const float* uW1 = (const float*)d_in[9];
    const float* ub1 = (const float*)d_in[10];
    const float* uW2 = (const float*)d_in[11];
    const float* ub2 = (const float*)d_in[12];
    const float* lng = (const float*)d_in[13];
    const float* lnb = (const float*)d_in[14];
    const float* resW = (const float*)d_in[15];
    float* out = (float*)d_out;

    // workspace layout (bytes) — total ~38.6 MB (< out bytes = 51.2 MB)
    char* ws = (char*)d_ws;
    unsigned short* y16 = (unsigned short*)(ws + 0);   // 25.6 MB
    uint2* brec = (uint2*)(ws + 25600000);             // 12.8 MB
    int* bcnt = (int*)(ws + 38400000);                 // 25,000 B
    int* alloc = (int*)(ws + 38425000);                // 4 B (adjacent: one memset)
    int* bstart = (int*)(ws + 38425004);               // 25,000 B
    int* bcursor = (int*)(ws + 38450004);              // 25,000 B
    unsigned short* w1t = (unsigned short*)(ws + 38475008);   // 65,536 B (16-aligned)
    unsigned short* w2t = (unsigned short*)(ws + 38540544);   // 32,768 B
    unsigned short* rest = (unsigned short*)(ws + 38573312);  // 32,768 B
    unsigned short* aggt = (unsigned short*)(ws + 38606080);  // 32,768 B -> 38,638,848
    float* agg = out;  // aliased onto d_out (safe: block-local rows in K4)

    const int* src = ei;
    const int* dst = ei + N_EDGES;

    hipMemsetAsync(bcnt, 0, N_BUCKETS * 4 + 4, stream);  // bcnt + alloc

    kw<<<320, 256, 0, stream>>>(uW1, uW2, resW, aggW, w1t, w2t, rest, aggt);
    k1_y<<<N_NODES / 32, 256, 0, stream>>>(x, aggt, aggb, y16);
    pe0<<<N_EDGES / 1024, 256, 0, stream>>>(dst, bcnt);
    p2b<<<(N_BUCKETS + 255) / 256, 256, 0, stream>>>(bcnt, bstart, bcursor, alloc);
    p3g<<<N_EDGES / 256, 256, 0, stream>>>(eattr, eW1, eb1, eW2, eb2, src, dst, bcursor, brec);
    pB<<<N_BUCKETS, 256, 0, stream>>>(y16, bstart, bcnt, brec, agg);
    k4_update<<<N_NODES / 32, 256, 0, stream>>>(x, agg, w1t, ub1, w2t, ub2, lng, lnb, rest, out);
}